// Round 3
// baseline (303.664 us; speedup 1.0000x reference)
//
#include <hip/hip_runtime.h>

#define BT 4096      // B*T
#define Dd 1024
#define Tt 2048

typedef __attribute__((ext_vector_type(8))) short bf16x8;
typedef __attribute__((ext_vector_type(4))) float f32x4;
typedef __attribute__((ext_vector_type(4))) unsigned u32x4;

__device__ __forceinline__ short f2bf(float f) {
  unsigned u = __builtin_bit_cast(unsigned, f);
  u = (u + 0x7FFFu + ((u >> 16) & 1u)) >> 16;
  return (short)u;
}
__device__ __forceinline__ float bf2f(short s) {
  unsigned u = ((unsigned)(unsigned short)s) << 16;
  return __builtin_bit_cast(float, u);
}
__device__ __forceinline__ unsigned cvt_pk_bf16(float a, float b) {
  unsigned r;
  asm("v_cvt_pk_bf16_f32 %0, %1, %2" : "=v"(r) : "v"(a), "v"(b));
  return r;
}

__device__ __forceinline__ void load_lds16(const void* gsrc, void* ldst) {
  __builtin_amdgcn_global_load_lds(
      (const __attribute__((address_space(1))) void*)gsrc,
      (__attribute__((address_space(3))) void*)ldst, 16, 0, 0);
}

// ---------------- x fp32 -> bf16 ----------------
__global__ __launch_bounds__(256) void k_cvt(const float* __restrict__ src,
                                             short* __restrict__ dst, int n4) {
  int i = blockIdx.x * 256 + threadIdx.x;
  if (i >= n4) return;
  float4 v = ((const float4*)src)[i];
  short4 o;
  o.x = f2bf(v.x); o.y = f2bf(v.y); o.z = f2bf(v.z); o.w = f2bf(v.w);
  ((short4*)dst)[i] = o;
}

// ------------- tiled weight transpose: src [K][N] f32 -> dst [N][K] bf16 -------------
__global__ __launch_bounds__(256) void k_wt2(const float* __restrict__ src,
                                             short* __restrict__ dst, int K, int N) {
  __shared__ float tile[64][65];
  const int n0 = blockIdx.x * 64, k0 = blockIdx.y * 64;
  const int c = threadIdx.x & 63, r4 = threadIdx.x >> 6;
#pragma unroll
  for (int i = 0; i < 16; ++i) {
    int r = i * 4 + r4;
    float v = 0.f;
    if (k0 + r < K && n0 + c < N) v = src[(size_t)(k0 + r) * N + n0 + c];
    tile[r][c] = v;
  }
  __syncthreads();
#pragma unroll
  for (int i = 0; i < 16; ++i) {
    int n = i * 4 + r4;
    if (n0 + n < N && k0 + c < K)
      dst[(size_t)(n0 + n) * K + k0 + c] = f2bf(tile[c][n]);
  }
}

// ---------------- generic bf16 MFMA GEMM: C[M,N] = A[M,K] @ Bt[N,K]^T + bias ----------
__global__ __launch_bounds__(256) void k_gemm(
    const short* __restrict__ A, const short* __restrict__ Bt,
    const float* __restrict__ bias, float* __restrict__ C,
    short* __restrict__ oq, short* __restrict__ ok_, short* __restrict__ ov,
    int M, int N, int K, int ldc, int mode) {
  __shared__ short As[128 * 32];
  __shared__ short Bs[128 * 32];
  const int tid = threadIdx.x;
  const int wave = tid >> 6, lane = tid & 63;
  const int bm = blockIdx.y * 128, bn = blockIdx.x * 128;
  const int wr = (wave >> 1) * 64, wc = (wave & 1) * 64;
  const int row = lane & 15, g = lane >> 4;
  f32x4 acc[4][4] = {};
  const int kTiles = K >> 5;
  for (int kt = 0; kt < kTiles; ++kt) {
    const int k0 = kt << 5;
    __syncthreads();
#pragma unroll
    for (int j = 0; j < 2; ++j) {
      int slot = (wave * 2 + j) * 64 + lane;
      int r = slot >> 2, s = slot & 3;
      load_lds16(A + (size_t)(bm + r) * K + k0 + s * 8, &As[slot * 8]);
      load_lds16(Bt + (size_t)(bn + r) * K + k0 + s * 8, &Bs[slot * 8]);
    }
    __syncthreads();
    bf16x8 af[4], bfr[4];
#pragma unroll
    for (int mi = 0; mi < 4; ++mi)
      af[mi] = *(const bf16x8*)&As[(wr + mi * 16 + row) * 32 + g * 8];
#pragma unroll
    for (int ni = 0; ni < 4; ++ni)
      bfr[ni] = *(const bf16x8*)&Bs[(wc + ni * 16 + row) * 32 + g * 8];
#pragma unroll
    for (int mi = 0; mi < 4; ++mi)
#pragma unroll
      for (int ni = 0; ni < 4; ++ni)
        acc[mi][ni] = __builtin_amdgcn_mfma_f32_16x16x32_bf16(af[mi], bfr[ni],
                                                              acc[mi][ni], 0, 0, 0);
  }
  const int row4 = g * 4;
#pragma unroll
  for (int mi = 0; mi < 4; ++mi)
#pragma unroll
    for (int ni = 0; ni < 4; ++ni) {
      int c = bn + wc + ni * 16 + row;
      if (c >= N) continue;
      float badd = bias ? bias[c] : 0.f;
#pragma unroll
      for (int rg = 0; rg < 4; ++rg) {
        int r = bm + wr + mi * 16 + row4 + rg;
        float val = acc[mi][ni][rg] + badd;
        if (mode == 0) {
          C[(size_t)r * ldc + c] = val;
        } else {
          int b = r >> 11, t = r & 2047;
          int sel = c >> 10, rem = c & 1023;
          short bv = f2bf(val);
          if (sel == 0)
            oq[((size_t)(b * 16 + (rem >> 6)) * 2048 + t) * 64 + (rem & 63)] = bv;
          else if (sel == 1)
            ok_[((size_t)(b * 16 + (rem >> 6)) * 2048 + t) * 64 + (rem & 63)] = bv;
          else
            ov[(size_t)(b * 2048 + t) * 1024 + rem] = bv;
        }
      }
    }
}

// ---------------- V transpose: vtmp [b,t,(h,dh)] bf16 -> vb [b,h,dh,t] bf16 ----------
__global__ __launch_bounds__(256) void k_vtrans(const short* __restrict__ vtmp,
                                                short* __restrict__ vb) {
  __shared__ short tile[64][68];
  const int bh = blockIdx.x, b = bh >> 4, h = bh & 15;
  const int t0 = blockIdx.y * 64;
  const int tid = threadIdx.x;
#pragma unroll
  for (int pass = 0; pass < 16; ++pass) {
    int r = pass * 4 + (tid >> 6);
    int c = tid & 63;
    tile[r][c] = vtmp[((size_t)(b * 2048) + t0 + r) * 1024 + h * 64 + c];
  }
  __syncthreads();
#pragma unroll
  for (int pass = 0; pass < 16; ++pass) {
    int r = pass * 4 + (tid >> 6);  // dh
    int c = tid & 63;               // t offset
    vb[(((size_t)b * 16 + h) * 64 + r) * 2048 + t0 + c] = tile[c][r];
  }
}

// ---------------- causal flash attention, swapped-operand form ----------------------
// S^T = mfma(K,Q): lane owns q = lane&15, k rows in regs -> in-lane softmax.
// O^T = mfma(V^T, P) with P packed in-register via v_cvt_pk_bf16_f32.
#define ATT_SCALE 0.18033688f  // 0.125 * log2(e)

__global__ __launch_bounds__(256) void k_attn(const short* __restrict__ Q,
                                              const short* __restrict__ Kg,
                                              const short* __restrict__ Vg,
                                              short* __restrict__ seqo) {
  __shared__ short Kt[2][64 * 64];
  __shared__ short Vt[2][64 * 64];
  const int wg = blockIdx.x;
  const int logical = (wg & 7) * 128 + (wg >> 3);  // bijective XCD chunking
  const int bh = logical >> 5;
  const int qt = 31 - (logical & 31);              // longest-first within chunk
  const int b = bh >> 4, h = bh & 15;
  const int tid = threadIdx.x, wave = tid >> 6, lane = tid & 63;
  const int ql = lane & 15, g = lane >> 4;
  const int qglob = qt * 64 + wave * 16 + ql;
  const short* qr = Q + ((size_t)bh * 2048 + qglob) * 64;
  bf16x8 qa[2];
  qa[0] = *(const bf16x8*)&qr[g * 8];
  qa[1] = *(const bf16x8*)&qr[32 + g * 8];
  f32x4 o[4] = {};
  float m = -1e30f, l = 0.f;
  const short* kgb = Kg + (size_t)bh * 2048 * 64;
  const short* vgb = Vg + (size_t)bh * 64 * 2048;

  auto stage = [&](int bi, int kt) {
    int kv0 = kt * 64;
#pragma unroll
    for (int j = 0; j < 2; ++j) {
      int slot = (wave * 2 + j) * 64 + lane;
      int r = slot >> 3, s = slot & 7;
      int ss = s ^ (r & 7);  // both-sides XOR swizzle (linear dest, swizzled source)
      load_lds16(kgb + (size_t)(kv0 + r) * 64 + ss * 8, &Kt[bi][slot * 8]);
      load_lds16(vgb + (size_t)r * 2048 + kv0 + ss * 8, &Vt[bi][slot * 8]);
    }
  };

  const int nkv = qt + 1;
  stage(0, 0);
  int cur = 0;
  for (int kt = 0; kt < nkv; ++kt) {
    __syncthreads();  // buf[cur] staged (vmcnt drained); buf[cur^1] free
    if (kt + 1 < nkv) stage(cur ^ 1, kt + 1);
    const short* Kc = Kt[cur];
    const short* Vc = Vt[cur];
    const int kv0 = kt * 64;
    // QK^T swapped: s4[nt][rg] = S[k = kv0+nt*16+g*4+rg][q = qglob]
    f32x4 s4[4];
#pragma unroll
    for (int nt = 0; nt < 4; ++nt) {
      int krow = nt * 16 + ql;
      f32x4 s = {0.f, 0.f, 0.f, 0.f};
#pragma unroll
      for (int kc = 0; kc < 2; ++kc) {
        int sl = (kc * 4 + g) ^ (krow & 7);
        bf16x8 af = *(const bf16x8*)&Kc[krow * 64 + sl * 8];
        s = __builtin_amdgcn_mfma_f32_16x16x32_bf16(af, qa[kc], s, 0, 0, 0);
      }
      s4[nt] = s;
    }
    // scale + causal mask (diagonal tile only) + in-lane max
    float mt = -1e30f;
    const bool diag = (kt == qt);
#pragma unroll
    for (int nt = 0; nt < 4; ++nt)
#pragma unroll
      for (int rg = 0; rg < 4; ++rg) {
        float v = s4[nt][rg] * ATT_SCALE;
        if (diag) {
          int kk = kv0 + nt * 16 + g * 4 + rg;
          v = (kk <= qglob) ? v : -1e30f;
        }
        s4[nt][rg] = v;
        mt = fmaxf(mt, v);
      }
    mt = fmaxf(mt, __shfl_xor(mt, 16, 64));
    mt = fmaxf(mt, __shfl_xor(mt, 32, 64));
    float mnew = fmaxf(m, mt);
    float sf = __builtin_amdgcn_exp2f(m - mnew);
    m = mnew;
    float rs = 0.f;
#pragma unroll
    for (int nt = 0; nt < 4; ++nt)
#pragma unroll
      for (int rg = 0; rg < 4; ++rg) {
        float p = __builtin_amdgcn_exp2f(s4[nt][rg] - mnew);
        s4[nt][rg] = p;
        rs += p;
      }
    rs += __shfl_xor(rs, 16, 64);
    rs += __shfl_xor(rs, 32, 64);
    l = l * sf + rs;
#pragma unroll
    for (int nt = 0; nt < 4; ++nt) o[nt] *= sf;
    // pack P into PV B-fragments (k-bijection shared with V A-frag below)
    bf16x8 pf[2];
#pragma unroll
    for (int kc = 0; kc < 2; ++kc) {
      u32x4 w;
      w[0] = cvt_pk_bf16(s4[2 * kc][0], s4[2 * kc][1]);
      w[1] = cvt_pk_bf16(s4[2 * kc][2], s4[2 * kc][3]);
      w[2] = cvt_pk_bf16(s4[2 * kc + 1][0], s4[2 * kc + 1][1]);
      w[3] = cvt_pk_bf16(s4[2 * kc + 1][2], s4[2 * kc + 1][3]);
      pf[kc] = __builtin_bit_cast(bf16x8, w);
    }
    // O^T accumulate: o[nt2][rg] = O[d = nt2*16+g*4+rg][q]
#pragma unroll
    for (int nt2 = 0; nt2 < 4; ++nt2) {
      int d = nt2 * 16 + ql;
#pragma unroll
      for (int kc = 0; kc < 2; ++kc) {
        int kb = kc * 4 + (g >> 1);
        int sub = (g & 1) * 4;
        short4 lo = *(const short4*)&Vc[d * 64 + ((kb ^ (d & 7)) * 8) + sub];
        short4 hi = *(const short4*)&Vc[d * 64 + (((kb + 2) ^ (d & 7)) * 8) + sub];
        struct S2 { short4 a, b; } s2{lo, hi};
        bf16x8 vf = __builtin_bit_cast(bf16x8, s2);
        o[nt2] = __builtin_amdgcn_mfma_f32_16x16x32_bf16(vf, pf[kc], o[nt2], 0, 0, 0);
      }
    }
    cur ^= 1;
  }
  // epilogue: O^T -> LDS (swizzled) -> coalesced bf16 store of O
  __syncthreads();  // all waves done reading Kt/Vt
  float inv = 1.f / l;
  float* ep = (float*)&Kt[0][0] + wave * 1024;  // 4KB per wave
#pragma unroll
  for (int nt2 = 0; nt2 < 4; ++nt2) {
    f32x4 v = o[nt2] * inv;
    *(f32x4*)&ep[ql * 64 + (((nt2 * 4 + g) ^ (ql & 7)) << 2)] = v;
  }
  short* srow = seqo + ((size_t)b * 2048 + qt * 64 + wave * 16) * 1024 + h * 64;
#pragma unroll
  for (int p = 0; p < 8; ++p) {
    int prow = p * 2 + (lane >> 5);
    int d2 = (lane & 31) * 2;
    const float* rp = &ep[prow * 64 + (((d2 >> 2) ^ (prow & 7)) << 2) + (d2 & 3)];
    float2 vv = *(const float2*)rp;
    unsigned pk = cvt_pk_bf16(vv.x, vv.y);
    *(unsigned*)&srow[(size_t)prow * 1024 + d2] = pk;
  }
}

// ---------------- Plücker lines: Csm [b,t,272] -> u=(wl@J)/|wl|, r=rl/|rl| ----------
__global__ __launch_bounds__(256) void k_lines(const float* __restrict__ Cs,
                                               const float* __restrict__ Jm,
                                               float* __restrict__ u,
                                               float* __restrict__ rr) {
  int idx = blockIdx.x * 256 + threadIdx.x;
  if (idx >= 2 * 2048 * 16) return;
  int h = idx & 15, t = (idx >> 4) & 2047, b = idx >> 15;
  const float* rowx = Cs + (size_t)(b * 2048 + t) * 272;
  float w1[4], w2[4], r1[4], r2[4];
  if (t == 0) {
#pragma unroll
    for (int i = 0; i < 4; ++i) w1[i] = 0.f;
  } else {
    const float* prev = Cs + (size_t)(b * 2048 + t - 1) * 272;
#pragma unroll
    for (int i = 0; i < 4; ++i) w1[i] = prev[h * 4 + i];
  }
#pragma unroll
  for (int i = 0; i < 4; ++i) {
    w2[i] = rowx[64 + h * 4 + i];
    r1[i] = rowx[128 + h * 4 + i];
    r2[i] = rowx[192 + h * 4 + i];
  }
  const int pi[6] = {0, 0, 0, 1, 1, 2}, pj[6] = {1, 2, 3, 2, 3, 3};
  float wl[6], rl[6], nw = 0.f, nr = 0.f;
#pragma unroll
  for (int e = 0; e < 6; ++e) {
    wl[e] = w1[pi[e]] * w2[pj[e]] - w1[pj[e]] * w2[pi[e]];
    rl[e] = r1[pi[e]] * r2[pj[e]] - r1[pj[e]] * r2[pi[e]];
    nw += wl[e] * wl[e];
    nr += rl[e] * rl[e];
  }
  nw = 1.f / fmaxf(sqrtf(nw), 1e-12f);
  nr = 1.f / fmaxf(sqrtf(nr), 1e-12f);
  size_t base = (((size_t)b * 16 + h) * 2048 + t) * 6;
#pragma unroll
  for (int jc = 0; jc < 6; ++jc) {
    float s = 0.f;
#pragma unroll
    for (int i = 0; i < 6; ++i) s += wl[i] * Jm[i * 6 + jc];
    u[base + jc] = s * nw;
    rr[base + jc] = rl[jc] * nr;
  }
}

// ------------- decayed prefix scan per channel: w[bh][ch][t] = S_t[p][q] -------------
__global__ __launch_bounds__(256) void k_scanw(const float* __restrict__ u,
                                               float* __restrict__ w,
                                               const float* __restrict__ decays) {
  __shared__ float wtot[4];
  const int ch = blockIdx.x;   // 0..35
  const int bh = blockIdx.y;   // 0..31
  const float d = decays[bh & 15];
  const int p = ch / 6, q = ch % 6;
  const int tid = threadIdx.x, lane = tid & 63, wv = tid >> 6;
  const float* ub = u + (size_t)bh * 2048 * 6;
  const int t0 = tid * 8;
  float z[8];
  float a = 0.f;
#pragma unroll
  for (int i = 0; i < 8; ++i) {
    float up = ub[(t0 + i) * 6 + p], uq = ub[(t0 + i) * 6 + q];
    z[i] = up * uq;
    a = d * (a + z[i]);
  }
  float d8 = d * d; d8 *= d8; d8 *= d8;
  float I = a;
  float ds = d8;
#pragma unroll
  for (int s = 1; s < 64; s <<= 1) {
    float v = __shfl_up(I, s, 64);
    if (lane >= s) I += ds * v;
    ds *= ds;
  }
  if (lane == 63) wtot[wv] = I;
  __syncthreads();
  float carry = 0.f;
  for (int w2 = 0; w2 < wv; ++w2) carry = carry * ds + wtot[w2];
  float dlp1 = exp2f(log2f(d8) * (float)(lane + 1));
  float Ig = I + dlp1 * carry;
  float E = __shfl_up(Ig, 1, 64);
  if (lane == 0) E = carry;
  float S = E;
  float out[8];
#pragma unroll
  for (int i = 0; i < 8; ++i) {
    out[i] = S;
    S = d * (S + z[i]);
  }
  float4* wp = (float4*)(w + ((size_t)bh * 36 + ch) * 2048 + t0);
  wp[0] = make_float4(out[0], out[1], out[2], out[3]);
  wp[1] = make_float4(out[4], out[5], out[6], out[7]);
}

// ------------- scores[bh][t] = sum_ch r[p]*r[q] * w[bh][ch][t] ----------------------
__global__ __launch_bounds__(256) void k_scandot(const float* __restrict__ rr,
                                                 const float* __restrict__ w,
                                                 float* __restrict__ scores) {
  const int bh = blockIdx.y;
  const int t = blockIdx.x * 256 + threadIdx.x;
  const float* rb = rr + ((size_t)bh * 2048 + t) * 6;
  float r[6];
#pragma unroll
  for (int i = 0; i < 6; ++i) r[i] = rb[i];
  const float* wb = w + (size_t)bh * 36 * 2048 + t;
  float acc = 0.f;
#pragma unroll
  for (int ch = 0; ch < 36; ++ch)
    acc += r[ch / 6] * r[ch % 6] * wb[(size_t)ch * 2048];
  scores[(size_t)bh * 2048 + t] = acc;
}

// ---------------- gate: gmean[b,t] = mean_h sig(score*scale_h)*sig(memg) -----------
__global__ __launch_bounds__(256) void k_gate(const float* __restrict__ scores,
                                              const float* __restrict__ Cs,
                                              const float* __restrict__ memg_b,
                                              const float* __restrict__ mem_scale,
                                              float* __restrict__ gmean) {
  int idx = blockIdx.x * 256 + threadIdx.x;
  if (idx >= BT) return;
  int b = idx >> 11, t = idx & 2047;
  float acc = 0.f;
#pragma unroll
  for (int h = 0; h < 16; ++h) {
    float s = scores[((size_t)(b * 16 + h) * 2048) + t];
    float gl = Cs[(size_t)idx * 272 + 256 + h] + memg_b[h];
    float a = 1.f / (1.f + __expf(-s * mem_scale[h]));
    float gg = 1.f / (1.f + __expf(-gl));
    acc += a * gg;
  }
  gmean[idx] = acc * (1.f / 16.f);
}

// ---------------- fuse: Fb = bf16(seq_bf16 + gmean*memval) ----------------
__global__ __launch_bounds__(256) void k_fuse(const short* __restrict__ s,
                                              const float* __restrict__ mv,
                                              const float* __restrict__ gm,
                                              short* __restrict__ dst, int n4) {
  int i = blockIdx.x * 256 + threadIdx.x;
  if (i >= n4) return;
  float gg = gm[i >> 8];
  short4 a = ((const short4*)s)[i];
  float4 m = ((const float4*)mv)[i];
  short4 o;
  o.x = f2bf(bf2f(a.x) + gg * m.x);
  o.y = f2bf(bf2f(a.y) + gg * m.y);
  o.z = f2bf(bf2f(a.z) + gg * m.z);
  o.w = f2bf(bf2f(a.w) + gg * m.w);
  ((short4*)dst)[i] = o;
}

extern "C" void kernel_launch(void* const* d_in, const int* in_sizes, int n_in,
                              void* d_out, int out_size, void* d_ws, size_t ws_size,
                              hipStream_t stream) {
  const float* x = (const float*)d_in[0];
  const float* qkv_w = (const float*)d_in[1];
  const float* qkv_b = (const float*)d_in[2];
  const float* w1w = (const float*)d_in[3];
  const float* w2w = (const float*)d_in[4];
  const float* w1r = (const float*)d_in[5];
  const float* w2r = (const float*)d_in[6];
  const float* memv_w = (const float*)d_in[7];
  const float* memv_b = (const float*)d_in[8];
  const float* memg_w = (const float*)d_in[9];
  const float* memg_b = (const float*)d_in[10];
  const float* mem_scale = (const float*)d_in[11];
  const float* out_w = (const float*)d_in[12];
  const float* out_b = (const float*)d_in[13];
  const float* Jm = (const float*)d_in[14];
  const float* decays = (const float*)d_in[15];

  char* w = (char*)d_ws;
  size_t off = 0;
  auto alloc = [&](size_t bytes) -> void* {
    void* p = w + off;
    off += (bytes + 255) & ~(size_t)255;
    return p;
  };
  short* xb = (short*)alloc((size_t)BT * Dd * 2);
  short* WTqkv = (short*)alloc((size_t)3072 * 1024 * 2);
  short* WTsm = (short*)alloc((size_t)384 * 1024 * 2);
  short* WTmv = (short*)alloc((size_t)1024 * 1024 * 2);
  short* WTout = (short*)alloc((size_t)1024 * 1024 * 2);
  short* qb = (short*)alloc((size_t)32 * 2048 * 64 * 2);
  short* kb = (short*)alloc((size_t)32 * 2048 * 64 * 2);
  short* vtmp = (short*)alloc((size_t)BT * 1024 * 2);
  short* vb = (short*)alloc((size_t)32 * 64 * 2048 * 2);
  float* Csm = (float*)alloc((size_t)BT * 272 * 4);
  float* ua = (float*)alloc((size_t)32 * 2048 * 6 * 4);
  float* ra = (float*)alloc((size_t)32 * 2048 * 6 * 4);
  float* sc = (float*)alloc((size_t)32 * 2048 * 4);
  float* gm = (float*)alloc((size_t)BT * 4);
  float* mval = (float*)alloc((size_t)BT * 1024 * 4);
  short* seqo = (short*)alloc((size_t)BT * 1024 * 2);   // bf16 now
  short* Fb = (short*)alloc((size_t)BT * Dd * 2);
  // scan state buffer (32*36*2048 fp32 = 9.4 MB) aliases qb+kb (16.8 MB),
  // which are dead after k_attn (stream-ordered before k_scanw).
  float* wscan = (float*)qb;
  (void)ws_size; (void)in_sizes; (void)n_in; (void)out_size;

  // prep
  k_cvt<<<(BT * Dd / 4 + 255) / 256, 256, 0, stream>>>(x, xb, BT * Dd / 4);
  k_wt2<<<dim3(48, 16), 256, 0, stream>>>(qkv_w, WTqkv, 1024, 3072);
  k_wt2<<<dim3(1, 16), 256, 0, stream>>>(w1w, WTsm + (size_t)0 * 1024, 1024, 64);
  k_wt2<<<dim3(1, 16), 256, 0, stream>>>(w2w, WTsm + (size_t)64 * 1024, 1024, 64);
  k_wt2<<<dim3(1, 16), 256, 0, stream>>>(w1r, WTsm + (size_t)128 * 1024, 1024, 64);
  k_wt2<<<dim3(1, 16), 256, 0, stream>>>(w2r, WTsm + (size_t)192 * 1024, 1024, 64);
  k_wt2<<<dim3(1, 16), 256, 0, stream>>>(memg_w, WTsm + (size_t)256 * 1024, 1024, 16);
  k_wt2<<<dim3(16, 16), 256, 0, stream>>>(memv_w, WTmv, 1024, 1024);
  k_wt2<<<dim3(16, 16), 256, 0, stream>>>(out_w, WTout, 1024, 1024);

  // GEMMs
  k_gemm<<<dim3(24, 32), 256, 0, stream>>>(xb, WTqkv, qkv_b, nullptr, qb, kb, vtmp,
                                           BT, 3072, 1024, 0, 1);
  k_vtrans<<<dim3(32, 32), 256, 0, stream>>>(vtmp, vb);
  k_gemm<<<dim3(3, 32), 256, 0, stream>>>(xb, WTsm, nullptr, Csm, nullptr, nullptr,
                                          nullptr, BT, 272, 1024, 272, 0);
  k_gemm<<<dim3(8, 32), 256, 0, stream>>>(xb, WTmv, memv_b, mval, nullptr, nullptr,
                                          nullptr, BT, 1024, 1024, 1024, 0);

  // attention: 1024 one-q-tile blocks, XCD-chunked, longest-first
  k_attn<<<1024, 256, 0, stream>>>(qb, kb, vb, seqo);

  // memory path
  k_lines<<<(2 * 2048 * 16 + 255) / 256, 256, 0, stream>>>(Csm, Jm, ua, ra);
  k_scanw<<<dim3(36, 32), 256, 0, stream>>>(ua, wscan, decays);
  k_scandot<<<dim3(8, 32), 256, 0, stream>>>(ra, wscan, sc);
  k_gate<<<(BT + 255) / 256, 256, 0, stream>>>(sc, Csm, memg_b, mem_scale, gm);

  // fuse + final GEMM
  k_fuse<<<(BT * Dd / 4 + 255) / 256, 256, 0, stream>>>(seqo, mval, gm, Fb, BT * Dd / 4);
  k_gemm<<<dim3(8, 32), 256, 0, stream>>>(Fb, WTout, out_b, (float*)d_out, nullptr,
                                          nullptr, nullptr, BT, 1024, 1024, 1024, 0);
}

// Round 4
// 278.007 us; speedup vs baseline: 1.0923x; 1.0923x over previous
//
#include <hip/hip_runtime.h>

#define BT 4096      // B*T
#define Dd 1024
#define Tt 2048

typedef __attribute__((ext_vector_type(8))) short bf16x8;
typedef __attribute__((ext_vector_type(4))) float f32x4;
typedef __attribute__((ext_vector_type(4))) unsigned u32x4;

__device__ __forceinline__ short f2bf(float f) {
  unsigned u = __builtin_bit_cast(unsigned, f);
  u = (u + 0x7FFFu + ((u >> 16) & 1u)) >> 16;
  return (short)u;
}
__device__ __forceinline__ float bf2f(short s) {
  unsigned u = ((unsigned)(unsigned short)s) << 16;
  return __builtin_bit_cast(float, u);
}
__device__ __forceinline__ unsigned cvt_pk_bf16(float a, float b) {
  unsigned r;
  asm("v_cvt_pk_bf16_f32 %0, %1, %2" : "=v"(r) : "v"(a), "v"(b));
  return r;
}

__device__ __forceinline__ void load_lds16(const void* gsrc, void* ldst) {
  __builtin_amdgcn_global_load_lds(
      (const __attribute__((address_space(1))) void*)gsrc,
      (__attribute__((address_space(3))) void*)ldst, 16, 0, 0);
}

// ---------------- x fp32 -> bf16 ----------------
__global__ __launch_bounds__(256) void k_cvt(const float* __restrict__ src,
                                             short* __restrict__ dst, int n4) {
  int i = blockIdx.x * 256 + threadIdx.x;
  if (i >= n4) return;
  float4 v = ((const float4*)src)[i];
  short4 o;
  o.x = f2bf(v.x); o.y = f2bf(v.y); o.z = f2bf(v.z); o.w = f2bf(v.w);
  ((short4*)dst)[i] = o;
}

// ------------- tiled weight transpose: src [K][N] f32 -> dst [N][K] bf16 -------------
__global__ __launch_bounds__(256) void k_wt2(const float* __restrict__ src,
                                             short* __restrict__ dst, int K, int N) {
  __shared__ float tile[64][65];
  const int n0 = blockIdx.x * 64, k0 = blockIdx.y * 64;
  const int c = threadIdx.x & 63, r4 = threadIdx.x >> 6;
#pragma unroll
  for (int i = 0; i < 16; ++i) {
    int r = i * 4 + r4;
    float v = 0.f;
    if (k0 + r < K && n0 + c < N) v = src[(size_t)(k0 + r) * N + n0 + c];
    tile[r][c] = v;
  }
  __syncthreads();
#pragma unroll
  for (int i = 0; i < 16; ++i) {
    int n = i * 4 + r4;
    if (n0 + n < N && k0 + c < K)
      dst[(size_t)(n0 + n) * K + k0 + c] = f2bf(tile[c][n]);
  }
}

// ---------------- generic bf16 MFMA GEMM: C[M,N] = A[M,K] @ Bt[N,K]^T + bias ----------
__global__ __launch_bounds__(256) void k_gemm(
    const short* __restrict__ A, const short* __restrict__ Bt,
    const float* __restrict__ bias, float* __restrict__ C,
    short* __restrict__ oq, short* __restrict__ ok_, short* __restrict__ ov,
    int M, int N, int K, int ldc, int mode) {
  __shared__ short As[128 * 32];
  __shared__ short Bs[128 * 32];
  const int tid = threadIdx.x;
  const int wave = tid >> 6, lane = tid & 63;
  const int bm = blockIdx.y * 128, bn = blockIdx.x * 128;
  const int wr = (wave >> 1) * 64, wc = (wave & 1) * 64;
  const int row = lane & 15, g = lane >> 4;
  f32x4 acc[4][4] = {};
  const int kTiles = K >> 5;
  for (int kt = 0; kt < kTiles; ++kt) {
    const int k0 = kt << 5;
    __syncthreads();
#pragma unroll
    for (int j = 0; j < 2; ++j) {
      int slot = (wave * 2 + j) * 64 + lane;
      int r = slot >> 2, s = slot & 3;
      load_lds16(A + (size_t)(bm + r) * K + k0 + s * 8, &As[slot * 8]);
      load_lds16(Bt + (size_t)(bn + r) * K + k0 + s * 8, &Bs[slot * 8]);
    }
    __syncthreads();
    bf16x8 af[4], bfr[4];
#pragma unroll
    for (int mi = 0; mi < 4; ++mi)
      af[mi] = *(const bf16x8*)&As[(wr + mi * 16 + row) * 32 + g * 8];
#pragma unroll
    for (int ni = 0; ni < 4; ++ni)
      bfr[ni] = *(const bf16x8*)&Bs[(wc + ni * 16 + row) * 32 + g * 8];
#pragma unroll
    for (int mi = 0; mi < 4; ++mi)
#pragma unroll
      for (int ni = 0; ni < 4; ++ni)
        acc[mi][ni] = __builtin_amdgcn_mfma_f32_16x16x32_bf16(af[mi], bfr[ni],
                                                              acc[mi][ni], 0, 0, 0);
  }
  const int row4 = g * 4;
#pragma unroll
  for (int mi = 0; mi < 4; ++mi)
#pragma unroll
    for (int ni = 0; ni < 4; ++ni) {
      int c = bn + wc + ni * 16 + row;
      if (c >= N) continue;
      float badd = bias ? bias[c] : 0.f;
#pragma unroll
      for (int rg = 0; rg < 4; ++rg) {
        int r = bm + wr + mi * 16 + row4 + rg;
        float val = acc[mi][ni][rg] + badd;
        if (mode == 0) {
          C[(size_t)r * ldc + c] = val;
        } else {
          int b = r >> 11, t = r & 2047;
          int sel = c >> 10, rem = c & 1023;
          short bv = f2bf(val);
          if (sel == 0)
            oq[((size_t)(b * 16 + (rem >> 6)) * 2048 + t) * 64 + (rem & 63)] = bv;
          else if (sel == 1)
            ok_[((size_t)(b * 16 + (rem >> 6)) * 2048 + t) * 64 + (rem & 63)] = bv;
          else
            ov[(size_t)(b * 2048 + t) * 1024 + rem] = bv;
        }
      }
    }
}

// -------- V transpose + PV k-permute: vtmp [b,t,(h,dh)] -> vb [b,h,dh,tau(t)] --------
// tau places t = 32kc+16p+4g+rg at pos = 32kc+8g+4p+rg so the PV A-fragment is one
// contiguous (swizzled) b128 read matching the in-register P pack's k order.
__global__ __launch_bounds__(256) void k_vtrans(const short* __restrict__ vtmp,
                                                short* __restrict__ vb) {
  __shared__ short tile[64][68];
  const int bh = blockIdx.x, b = bh >> 4, h = bh & 15;
  const int t0 = blockIdx.y * 64;
  const int tid = threadIdx.x;
#pragma unroll
  for (int pass = 0; pass < 16; ++pass) {
    int r = pass * 4 + (tid >> 6);
    int c = tid & 63;
    tile[r][c] = vtmp[((size_t)(b * 2048) + t0 + r) * 1024 + h * 64 + c];
  }
  __syncthreads();
#pragma unroll
  for (int pass = 0; pass < 16; ++pass) {
    int r = pass * 4 + (tid >> 6);  // dh
    int c = tid & 63;               // t offset within tile
    int cp = (c & 32) | (((c >> 2) & 3) << 3) | (((c >> 4) & 1) << 2) | (c & 3);
    vb[(((size_t)b * 16 + h) * 64 + r) * 2048 + t0 + cp] = tile[c][r];
  }
}

// ---------------- causal flash attention, swapped-operand, balanced pairs -----------
#define ATT_SCALE 0.18033688f  // 0.125 * log2(e)

__device__ __forceinline__ void attn_core(const bf16x8 qa[2], f32x4 o[4],
                                          float& m, float& l,
                                          const short* __restrict__ Kc,
                                          const short* __restrict__ Vc,
                                          int qt, int kt, int qglob,
                                          int ql, int g) {
  const int kv0 = kt * 64;
  f32x4 s4[4];
#pragma unroll
  for (int nt = 0; nt < 4; ++nt) {
    int krow = nt * 16 + ql;
    f32x4 s = {0.f, 0.f, 0.f, 0.f};
#pragma unroll
    for (int kc = 0; kc < 2; ++kc) {
      int sl = (kc * 4 + g) ^ (krow & 7);
      bf16x8 af = *(const bf16x8*)&Kc[krow * 64 + sl * 8];
      s = __builtin_amdgcn_mfma_f32_16x16x32_bf16(af, qa[kc], s, 0, 0, 0);
    }
    s4[nt] = s;
  }
  float mt = -1e30f;
  const bool diag = (kt == qt);
#pragma unroll
  for (int nt = 0; nt < 4; ++nt)
#pragma unroll
    for (int rg = 0; rg < 4; ++rg) {
      float v = s4[nt][rg] * ATT_SCALE;
      if (diag) {
        int kk = kv0 + nt * 16 + g * 4 + rg;
        v = (kk <= qglob) ? v : -1e30f;
      }
      s4[nt][rg] = v;
      mt = fmaxf(mt, v);
    }
  mt = fmaxf(mt, __shfl_xor(mt, 16, 64));
  mt = fmaxf(mt, __shfl_xor(mt, 32, 64));
  float mnew = fmaxf(m, mt);
  float sf = __builtin_amdgcn_exp2f(m - mnew);
  m = mnew;
  float rs = 0.f;
#pragma unroll
  for (int nt = 0; nt < 4; ++nt)
#pragma unroll
    for (int rg = 0; rg < 4; ++rg) {
      float p = __builtin_amdgcn_exp2f(s4[nt][rg] - mnew);
      s4[nt][rg] = p;
      rs += p;
    }
  rs += __shfl_xor(rs, 16, 64);
  rs += __shfl_xor(rs, 32, 64);
  l = l * sf + rs;
#pragma unroll
  for (int nt = 0; nt < 4; ++nt) o[nt] *= sf;
  // pack P (k order matches vb's tau permutation)
  bf16x8 pf[2];
#pragma unroll
  for (int kc = 0; kc < 2; ++kc) {
    u32x4 w;
    w[0] = cvt_pk_bf16(s4[2 * kc][0], s4[2 * kc][1]);
    w[1] = cvt_pk_bf16(s4[2 * kc][2], s4[2 * kc][3]);
    w[2] = cvt_pk_bf16(s4[2 * kc + 1][0], s4[2 * kc + 1][1]);
    w[3] = cvt_pk_bf16(s4[2 * kc + 1][2], s4[2 * kc + 1][3]);
    pf[kc] = __builtin_bit_cast(bf16x8, w);
  }
  // O^T accumulate, V fragment = single swizzled b128 (same pattern as K read)
#pragma unroll
  for (int nt2 = 0; nt2 < 4; ++nt2) {
    int d = nt2 * 16 + ql;
#pragma unroll
    for (int kc = 0; kc < 2; ++kc) {
      int sl = (kc * 4 + g) ^ (d & 7);
      bf16x8 vf = *(const bf16x8*)&Vc[d * 64 + sl * 8];
      o[nt2] = __builtin_amdgcn_mfma_f32_16x16x32_bf16(vf, pf[kc], o[nt2], 0, 0, 0);
    }
  }
}

__device__ __forceinline__ void attn_epi(const f32x4 o[4], float l,
                                         short* __restrict__ seqo, float* ep,
                                         int b, int h, int qt, int wave, int lane) {
  const int ql = lane & 15, g = lane >> 4;
  float inv = 1.f / l;
#pragma unroll
  for (int nt2 = 0; nt2 < 4; ++nt2) {
    f32x4 v = o[nt2] * inv;
    *(f32x4*)&ep[ql * 64 + (((nt2 * 4 + g) ^ (ql & 7)) << 2)] = v;
  }
  short* srow = seqo + ((size_t)b * 2048 + qt * 64 + wave * 16) * 1024 + h * 64;
#pragma unroll
  for (int p = 0; p < 8; ++p) {
    int prow = p * 2 + (lane >> 5);
    int d2 = (lane & 31) * 2;
    const float* rp = &ep[prow * 64 + (((d2 >> 2) ^ (prow & 7)) << 2) + (d2 & 3)];
    float2 vv = *(const float2*)rp;
    *(unsigned*)&srow[(size_t)prow * 1024 + d2] = cvt_pk_bf16(vv.x, vv.y);
  }
}

// 256 blocks x 512 threads. Each 256-thread half handles complementary pair
// (qtA=pi, qtB=31-pi) of the SAME bh sequentially: exactly 33 staged steps per
// half -> perfectly balanced blocks regardless of dispatch mapping.
__global__ __launch_bounds__(512, 4) void k_attn(const short* __restrict__ Q,
                                                 const short* __restrict__ Kg,
                                                 const short* __restrict__ Vg,
                                                 short* __restrict__ seqo) {
  __shared__ short Kt[2][2][64 * 64];  // [half][buf] 32KB
  __shared__ short Vt[2][2][64 * 64];  // 32KB
  const int wg = blockIdx.x;
  const int x = wg & 7, s = wg >> 3;       // XCD x gets bh in {4x..4x+3}
  const int bh = 4 * x + (s >> 3);
  const int tid = threadIdx.x;
  const int half = tid >> 8;
  const int pi = ((s & 7) << 1) + half;    // 0..15
  const int qtA = pi, qtB = 31 - pi;
  const int b = bh >> 4, h = bh & 15;
  const int wave = (tid >> 6) & 3, lane = tid & 63;
  const int ql = lane & 15, g = lane >> 4;
  const short* qbase = Q + (size_t)bh * 2048 * 64;
  const int qgA = qtA * 64 + wave * 16 + ql;
  const int qgB = qtB * 64 + wave * 16 + ql;
  bf16x8 qaA[2], qaB[2];
  {
    const short* qr = qbase + (size_t)qgA * 64;
    qaA[0] = *(const bf16x8*)&qr[g * 8];
    qaA[1] = *(const bf16x8*)&qr[32 + g * 8];
    qr = qbase + (size_t)qgB * 64;
    qaB[0] = *(const bf16x8*)&qr[g * 8];
    qaB[1] = *(const bf16x8*)&qr[32 + g * 8];
  }
  f32x4 oA[4] = {}, oB[4] = {};
  float mA = -1e30f, lA = 0.f, mB = -1e30f, lB = 0.f;
  const short* kgb = Kg + (size_t)bh * 2048 * 64;
  const short* vgb = Vg + (size_t)bh * 64 * 2048;

  auto stage = [&](int buf, int kt) {
    int kv0 = kt * 64;
#pragma unroll
    for (int j = 0; j < 2; ++j) {
      int slot = (wave * 2 + j) * 64 + lane;
      int r = slot >> 3, s8 = slot & 7;
      int ss = s8 ^ (r & 7);
      load_lds16(kgb + (size_t)(kv0 + r) * 64 + ss * 8, &Kt[half][buf][slot * 8]);
      load_lds16(vgb + (size_t)r * 2048 + kv0 + ss * 8, &Vt[half][buf][slot * 8]);
    }
  };

  stage(0, 0);
  int cur = 0;
  for (int it = 0; it < 33; ++it) {
    __syncthreads();  // buf[cur] staged for this half; buf[cur^1] free
    if (it < 32) {
      int nit = it + 1;
      int nkt = (nit <= qtB) ? nit : nit - qtB - 1;
      stage(cur ^ 1, nkt);
    }
    const short* Kc = Kt[half][cur];
    const short* Vc = Vt[half][cur];
    if (it <= qtB)
      attn_core(qaB, oB, mB, lB, Kc, Vc, qtB, it, qgB, ql, g);
    else
      attn_core(qaA, oA, mA, lA, Kc, Vc, qtA, it - qtB - 1, qgA, ql, g);
    cur ^= 1;
  }
  __syncthreads();  // all waves done with Kt/Vt; reuse Kt[half] as epi scratch
  float* ep = (float*)&Kt[half][0][0] + wave * 1024;  // 4KB per wave
  attn_epi(oB, lB, seqo, ep, b, h, qtB, wave, lane);
  attn_epi(oA, lA, seqo, ep, b, h, qtA, wave, lane);
}

// ---------------- Plücker lines: Csm [b,t,272] -> u=(wl@J)/|wl|, r=rl/|rl| ----------
__global__ __launch_bounds__(256) void k_lines(const float* __restrict__ Cs,
                                               const float* __restrict__ Jm,
                                               float* __restrict__ u,
                                               float* __restrict__ rr) {
  int idx = blockIdx.x * 256 + threadIdx.x;
  if (idx >= 2 * 2048 * 16) return;
  int h = idx & 15, t = (idx >> 4) & 2047, b = idx >> 15;
  const float* rowx = Cs + (size_t)(b * 2048 + t) * 272;
  float w1[4], w2[4], r1[4], r2[4];
  if (t == 0) {
#pragma unroll
    for (int i = 0; i < 4; ++i) w1[i] = 0.f;
  } else {
    const float* prev = Cs + (size_t)(b * 2048 + t - 1) * 272;
#pragma unroll
    for (int i = 0; i < 4; ++i) w1[i] = prev[h * 4 + i];
  }
#pragma unroll
  for (int i = 0; i < 4; ++i) {
    w2[i] = rowx[64 + h * 4 + i];
    r1[i] = rowx[128 + h * 4 + i];
    r2[i] = rowx[192 + h * 4 + i];
  }
  const int pi[6] = {0, 0, 0, 1, 1, 2}, pj[6] = {1, 2, 3, 2, 3, 3};
  float wl[6], rl[6], nw = 0.f, nr = 0.f;
#pragma unroll
  for (int e = 0; e < 6; ++e) {
    wl[e] = w1[pi[e]] * w2[pj[e]] - w1[pj[e]] * w2[pi[e]];
    rl[e] = r1[pi[e]] * r2[pj[e]] - r1[pj[e]] * r2[pi[e]];
    nw += wl[e] * wl[e];
    nr += rl[e] * rl[e];
  }
  nw = 1.f / fmaxf(sqrtf(nw), 1e-12f);
  nr = 1.f / fmaxf(sqrtf(nr), 1e-12f);
  size_t base = (((size_t)b * 16 + h) * 2048 + t) * 6;
#pragma unroll
  for (int jc = 0; jc < 6; ++jc) {
    float s = 0.f;
#pragma unroll
    for (int i = 0; i < 6; ++i) s += wl[i] * Jm[i * 6 + jc];
    u[base + jc] = s * nw;
    rr[base + jc] = rl[jc] * nr;
  }
}

// ------------- decayed prefix scan per channel: w[bh][ch][t] = S_t[p][q] -------------
__global__ __launch_bounds__(256) void k_scanw(const float* __restrict__ u,
                                               float* __restrict__ w,
                                               const float* __restrict__ decays) {
  __shared__ float wtot[4];
  const int ch = blockIdx.x;   // 0..35
  const int bh = blockIdx.y;   // 0..31
  const float d = decays[bh & 15];
  const int p = ch / 6, q = ch % 6;
  const int tid = threadIdx.x, lane = tid & 63, wv = tid >> 6;
  const float* ub = u + (size_t)bh * 2048 * 6;
  const int t0 = tid * 8;
  float z[8];
  float a = 0.f;
#pragma unroll
  for (int i = 0; i < 8; ++i) {
    float up = ub[(t0 + i) * 6 + p], uq = ub[(t0 + i) * 6 + q];
    z[i] = up * uq;
    a = d * (a + z[i]);
  }
  float d8 = d * d; d8 *= d8; d8 *= d8;
  float I = a;
  float ds = d8;
#pragma unroll
  for (int s = 1; s < 64; s <<= 1) {
    float v = __shfl_up(I, s, 64);
    if (lane >= s) I += ds * v;
    ds *= ds;
  }
  if (lane == 63) wtot[wv] = I;
  __syncthreads();
  float carry = 0.f;
  for (int w2 = 0; w2 < wv; ++w2) carry = carry * ds + wtot[w2];
  float dlp1 = exp2f(log2f(d8) * (float)(lane + 1));
  float Ig = I + dlp1 * carry;
  float E = __shfl_up(Ig, 1, 64);
  if (lane == 0) E = carry;
  float S = E;
  float out[8];
#pragma unroll
  for (int i = 0; i < 8; ++i) {
    out[i] = S;
    S = d * (S + z[i]);
  }
  float4* wp = (float4*)(w + ((size_t)bh * 36 + ch) * 2048 + t0);
  wp[0] = make_float4(out[0], out[1], out[2], out[3]);
  wp[1] = make_float4(out[4], out[5], out[6], out[7]);
}

// ------------- scores[bh][t] = sum_ch r[p]*r[q] * w[bh][ch][t] ----------------------
__global__ __launch_bounds__(256) void k_scandot(const float* __restrict__ rr,
                                                 const float* __restrict__ w,
                                                 float* __restrict__ scores) {
  const int bh = blockIdx.y;
  const int t = blockIdx.x * 256 + threadIdx.x;
  const float* rb = rr + ((size_t)bh * 2048 + t) * 6;
  float r[6];
#pragma unroll
  for (int i = 0; i < 6; ++i) r[i] = rb[i];
  const float* wb = w + (size_t)bh * 36 * 2048 + t;
  float acc = 0.f;
#pragma unroll
  for (int ch = 0; ch < 36; ++ch)
    acc += r[ch / 6] * r[ch % 6] * wb[(size_t)ch * 2048];
  scores[(size_t)bh * 2048 + t] = acc;
}

// ---------------- gate: gmean[b,t] = mean_h sig(score*scale_h)*sig(memg) -----------
__global__ __launch_bounds__(256) void k_gate(const float* __restrict__ scores,
                                              const float* __restrict__ Cs,
                                              const float* __restrict__ memg_b,
                                              const float* __restrict__ mem_scale,
                                              float* __restrict__ gmean) {
  int idx = blockIdx.x * 256 + threadIdx.x;
  if (idx >= BT) return;
  int b = idx >> 11, t = idx & 2047;
  float acc = 0.f;
#pragma unroll
  for (int h = 0; h < 16; ++h) {
    float s = scores[((size_t)(b * 16 + h) * 2048) + t];
    float gl = Cs[(size_t)idx * 272 + 256 + h] + memg_b[h];
    float a = 1.f / (1.f + __expf(-s * mem_scale[h]));
    float gg = 1.f / (1.f + __expf(-gl));
    acc += a * gg;
  }
  gmean[idx] = acc * (1.f / 16.f);
}

// ---------------- fuse: Fb = bf16(seq_bf16 + gmean*memval) ----------------
__global__ __launch_bounds__(256) void k_fuse(const short* __restrict__ s,
                                              const float* __restrict__ mv,
                                              const float* __restrict__ gm,
                                              short* __restrict__ dst, int n4) {
  int i = blockIdx.x * 256 + threadIdx.x;
  if (i >= n4) return;
  float gg = gm[i >> 8];
  short4 a = ((const short4*)s)[i];
  float4 m = ((const float4*)mv)[i];
  short4 o;
  o.x = f2bf(bf2f(a.x) + gg * m.x);
  o.y = f2bf(bf2f(a.y) + gg * m.y);
  o.z = f2bf(bf2f(a.z) + gg * m.z);
  o.w = f2bf(bf2f(a.w) + gg * m.w);
  ((short4*)dst)[i] = o;
}

extern "C" void kernel_launch(void* const* d_in, const int* in_sizes, int n_in,
                              void* d_out, int out_size, void* d_ws, size_t ws_size,
                              hipStream_t stream) {
  const float* x = (const float*)d_in[0];
  const float* qkv_w = (const float*)d_in[1];
  const float* qkv_b = (const float*)d_in[2];
  const float* w1w = (const float*)d_in[3];
  const float* w2w = (const float*)d_in[4];
  const float* w1r = (const float*)d_in[5];
  const float* w2r = (const float*)d_in[6];
  const float* memv_w = (const float*)d_in[7];
  const float* memv_b = (const float*)d_in[8];
  const float* memg_w = (const float*)d_in[9];
  const float* memg_b = (const float*)d_in[10];
  const float* mem_scale = (const float*)d_in[11];
  const float* out_w = (const float*)d_in[12];
  const float* out_b = (const float*)d_in[13];
  const float* Jm = (const float*)d_in[14];
  const float* decays = (const float*)d_in[15];

  char* w = (char*)d_ws;
  size_t off = 0;
  auto alloc = [&](size_t bytes) -> void* {
    void* p = w + off;
    off += (bytes + 255) & ~(size_t)255;
    return p;
  };
  short* xb = (short*)alloc((size_t)BT * Dd * 2);
  short* WTqkv = (short*)alloc((size_t)3072 * 1024 * 2);
  short* WTsm = (short*)alloc((size_t)384 * 1024 * 2);
  short* WTmv = (short*)alloc((size_t)1024 * 1024 * 2);
  short* WTout = (short*)alloc((size_t)1024 * 1024 * 2);
  short* qb = (short*)alloc((size_t)32 * 2048 * 64 * 2);
  short* kb = (short*)alloc((size_t)32 * 2048 * 64 * 2);
  short* vtmp = (short*)alloc((size_t)BT * 1024 * 2);
  short* vb = (short*)alloc((size_t)32 * 64 * 2048 * 2);
  float* Csm = (float*)alloc((size_t)BT * 272 * 4);
  float* ua = (float*)alloc((size_t)32 * 2048 * 6 * 4);
  float* ra = (float*)alloc((size_t)32 * 2048 * 6 * 4);
  float* sc = (float*)alloc((size_t)32 * 2048 * 4);
  float* gm = (float*)alloc((size_t)BT * 4);
  float* mval = (float*)alloc((size_t)BT * 1024 * 4);
  short* seqo = (short*)alloc((size_t)BT * 1024 * 2);   // bf16
  short* Fb = (short*)alloc((size_t)BT * Dd * 2);
  // scan state buffer (32*36*2048 fp32 = 9.4 MB) aliases qb+kb (16.8 MB),
  // which are dead after k_attn (stream-ordered before k_scanw).
  float* wscan = (float*)qb;
  (void)ws_size; (void)in_sizes; (void)n_in; (void)out_size;

  // prep
  k_cvt<<<(BT * Dd / 4 + 255) / 256, 256, 0, stream>>>(x, xb, BT * Dd / 4);
  k_wt2<<<dim3(48, 16), 256, 0, stream>>>(qkv_w, WTqkv, 1024, 3072);
  k_wt2<<<dim3(1, 16), 256, 0, stream>>>(w1w, WTsm + (size_t)0 * 1024, 1024, 64);
  k_wt2<<<dim3(1, 16), 256, 0, stream>>>(w2w, WTsm + (size_t)64 * 1024, 1024, 64);
  k_wt2<<<dim3(1, 16), 256, 0, stream>>>(w1r, WTsm + (size_t)128 * 1024, 1024, 64);
  k_wt2<<<dim3(1, 16), 256, 0, stream>>>(w2r, WTsm + (size_t)192 * 1024, 1024, 64);
  k_wt2<<<dim3(1, 16), 256, 0, stream>>>(memg_w, WTsm + (size_t)256 * 1024, 1024, 16);
  k_wt2<<<dim3(16, 16), 256, 0, stream>>>(memv_w, WTmv, 1024, 1024);
  k_wt2<<<dim3(16, 16), 256, 0, stream>>>(out_w, WTout, 1024, 1024);

  // GEMMs
  k_gemm<<<dim3(24, 32), 256, 0, stream>>>(xb, WTqkv, qkv_b, nullptr, qb, kb, vtmp,
                                           BT, 3072, 1024, 0, 1);
  k_vtrans<<<dim3(32, 32), 256, 0, stream>>>(vtmp, vb);
  k_gemm<<<dim3(3, 32), 256, 0, stream>>>(xb, WTsm, nullptr, Csm, nullptr, nullptr,
                                          nullptr, BT, 272, 1024, 272, 0);
  k_gemm<<<dim3(8, 32), 256, 0, stream>>>(xb, WTmv, memv_b, mval, nullptr, nullptr,
                                          nullptr, BT, 1024, 1024, 1024, 0);

  // attention: 256 balanced blocks x 512 threads
  k_attn<<<256, 512, 0, stream>>>(qb, kb, vb, seqo);

  // memory path
  k_lines<<<(2 * 2048 * 16 + 255) / 256, 256, 0, stream>>>(Csm, Jm, ua, ra);
  k_scanw<<<dim3(36, 32), 256, 0, stream>>>(ua, wscan, decays);
  k_scandot<<<dim3(8, 32), 256, 0, stream>>>(ra, wscan, sc);
  k_gate<<<(BT + 255) / 256, 256, 0, stream>>>(sc, Csm, memg_b, mem_scale, gm);

  // fuse + final GEMM
  k_fuse<<<(BT * Dd / 4 + 255) / 256, 256, 0, stream>>>(seqo, mval, gm, Fb, BT * Dd / 4);
  k_gemm<<<dim3(8, 32), 256, 0, stream>>>(Fb, WTout, out_b, (float*)d_out, nullptr,
                                          nullptr, nullptr, BT, 1024, 1024, 1024, 0);
}

// Round 5
// 226.125 us; speedup vs baseline: 1.3429x; 1.2294x over previous
//
#include <hip/hip_runtime.h>

#define BT 4096      // B*T
#define Dd 1024
#define Tt 2048

typedef __attribute__((ext_vector_type(8))) short bf16x8;
typedef __attribute__((ext_vector_type(4))) float f32x4;
typedef __attribute__((ext_vector_type(4))) unsigned u32x4;

__device__ __forceinline__ short f2bf(float f) {
  unsigned u = __builtin_bit_cast(unsigned, f);
  u = (u + 0x7FFFu + ((u >> 16) & 1u)) >> 16;
  return (short)u;
}
__device__ __forceinline__ float bf2f(short s) {
  unsigned u = ((unsigned)(unsigned short)s) << 16;
  return __builtin_bit_cast(float, u);
}
__device__ __forceinline__ unsigned cvt_pk_bf16(float a, float b) {
  unsigned r;
  asm("v_cvt_pk_bf16_f32 %0, %1, %2" : "=v"(r) : "v"(a), "v"(b));
  return r;
}

__device__ __forceinline__ void load_lds16(const void* gsrc, void* ldst) {
  __builtin_amdgcn_global_load_lds(
      (const __attribute__((address_space(1))) void*)gsrc,
      (__attribute__((address_space(3))) void*)ldst, 16, 0, 0);
}

// ---------------- x fp32 -> bf16 ----------------
__global__ __launch_bounds__(256) void k_cvt(const float* __restrict__ src,
                                             short* __restrict__ dst, int n4) {
  int i = blockIdx.x * 256 + threadIdx.x;
  if (i >= n4) return;
  float4 v = ((const float4*)src)[i];
  short4 o;
  o.x = f2bf(v.x); o.y = f2bf(v.y); o.z = f2bf(v.z); o.w = f2bf(v.w);
  ((short4*)dst)[i] = o;
}

// ------------- tiled weight transpose: src [K][N] f32 -> dst [N][K] bf16 -------------
__global__ __launch_bounds__(256) void k_wt2(const float* __restrict__ src,
                                             short* __restrict__ dst, int K, int N) {
  __shared__ float tile[64][65];
  const int n0 = blockIdx.x * 64, k0 = blockIdx.y * 64;
  const int c = threadIdx.x & 63, r4 = threadIdx.x >> 6;
#pragma unroll
  for (int i = 0; i < 16; ++i) {
    int r = i * 4 + r4;
    float v = 0.f;
    if (k0 + r < K && n0 + c < N) v = src[(size_t)(k0 + r) * N + n0 + c];
    tile[r][c] = v;
  }
  __syncthreads();
#pragma unroll
  for (int i = 0; i < 16; ++i) {
    int n = i * 4 + r4;
    if (n0 + n < N && k0 + c < K)
      dst[(size_t)(n0 + n) * K + k0 + c] = f2bf(tile[c][n]);
  }
}

// ------- batched small transposes into WTall rows 4096.. (w1w,w2w,w1r,w2r,memg) -----
__global__ __launch_bounds__(256) void k_wt5(const float* __restrict__ s0,
                                             const float* __restrict__ s1,
                                             const float* __restrict__ s2,
                                             const float* __restrict__ s3,
                                             const float* __restrict__ s4,
                                             short* __restrict__ dst) {
  __shared__ float tile[64][65];
  const int z = blockIdx.z;
  const float* src = z == 0 ? s0 : z == 1 ? s1 : z == 2 ? s2 : z == 3 ? s3 : s4;
  const int N = (z == 4) ? 16 : 64;
  const int rowoff = 4096 + z * 64;
  const int k0 = blockIdx.y * 64;
  const int c = threadIdx.x & 63, r4 = threadIdx.x >> 6;
#pragma unroll
  for (int i = 0; i < 16; ++i) {
    int r = i * 4 + r4;
    float v = 0.f;
    if (c < N) v = src[(size_t)(k0 + r) * N + c];
    tile[r][c] = v;
  }
  __syncthreads();
#pragma unroll
  for (int i = 0; i < 16; ++i) {
    int n = i * 4 + r4;
    if (n < N)
      dst[(size_t)(rowoff + n) * 1024 + k0 + c] = f2bf(tile[c][n]);
  }
}

// ---------------- bf16 MFMA GEMM, dbuf LDS, XCD-chunked, swapped epilogue ------------
// acc = mfma(B_frag, A_frag): lane owns C row m (lane&15) and 4 consecutive cols/reg.
// mode 0: C[m][n] fp32 (ldc) + bias.   mode 1: fused routing (qkv|memv|Csm).
__global__ __launch_bounds__(256) void k_gemm(
    const short* __restrict__ A, const short* __restrict__ Bt,
    const float* __restrict__ bias, float* __restrict__ C,
    const float* __restrict__ bias2,
    short* __restrict__ oq, short* __restrict__ ok_, short* __restrict__ ov,
    float* __restrict__ omv, float* __restrict__ ocs,
    int K, int ldc, int mode) {
  __shared__ short As[2][128 * 32];
  __shared__ short Bs[2][128 * 32];
  const int tid = threadIdx.x;
  const int wave = tid >> 6, lane = tid & 63;
  // XCD-chunked bijective remap: each XCD owns gridDim.y/8 M-panels x all N.
  const int wg = blockIdx.y * gridDim.x + blockIdx.x;
  const int xcd = wg & 7, idx = wg >> 3;
  const int m_t = xcd * (gridDim.y >> 3) + idx / gridDim.x;
  const int n_t = idx % gridDim.x;
  const int bm = m_t * 128, bn = n_t * 128;
  const int wr = (wave >> 1) * 64, wc = (wave & 1) * 64;
  const int ql = lane & 15, g = lane >> 4;
  f32x4 acc[4][4] = {};
  const int kTiles = K >> 5;

  auto stage = [&](int buf, int kt) {
    const int k0 = kt << 5;
#pragma unroll
    for (int j = 0; j < 2; ++j) {
      int slot = (wave * 2 + j) * 64 + lane;
      int r = slot >> 2, s = slot & 3;
      load_lds16(A + (size_t)(bm + r) * K + k0 + s * 8, &As[buf][slot * 8]);
      load_lds16(Bt + (size_t)(bn + r) * K + k0 + s * 8, &Bs[buf][slot * 8]);
    }
  };

  stage(0, 0);
  int cur = 0;
  for (int kt = 0; kt < kTiles; ++kt) {
    __syncthreads();  // buf[cur] staged (vmcnt drained); buf[cur^1] free
    if (kt + 1 < kTiles) stage(cur ^ 1, kt + 1);
    bf16x8 af[4], bfr[4];
#pragma unroll
    for (int mi = 0; mi < 4; ++mi)
      af[mi] = *(const bf16x8*)&As[cur][(wr + mi * 16 + ql) * 32 + g * 8];
#pragma unroll
    for (int ni = 0; ni < 4; ++ni)
      bfr[ni] = *(const bf16x8*)&Bs[cur][(wc + ni * 16 + ql) * 32 + g * 8];
#pragma unroll
    for (int mi = 0; mi < 4; ++mi)
#pragma unroll
      for (int ni = 0; ni < 4; ++ni)
        acc[mi][ni] = __builtin_amdgcn_mfma_f32_16x16x32_bf16(bfr[ni], af[mi],
                                                              acc[mi][ni], 0, 0, 0);
    cur ^= 1;
  }
  // epilogue: lane owns row m = bm+wr+mi*16+ql, cols n0..n0+3 per (ni)
#pragma unroll
  for (int mi = 0; mi < 4; ++mi) {
    const int m = bm + wr + mi * 16 + ql;
    const int b = m >> 11, t = m & 2047;
#pragma unroll
    for (int ni = 0; ni < 4; ++ni) {
      const int n0 = bn + wc + ni * 16 + g * 4;
      f32x4 v = acc[mi][ni];
      if (mode == 0) {
        const float4 b4 = *(const float4*)&bias[n0];
        v[0] += b4.x; v[1] += b4.y; v[2] += b4.z; v[3] += b4.w;
        *(f32x4*)&C[(size_t)m * ldc + n0] = v;
      } else {
        if (n0 < 3072) {
          const float4 b4 = *(const float4*)&bias[n0];
          v[0] += b4.x; v[1] += b4.y; v[2] += b4.z; v[3] += b4.w;
          uint2 pk = make_uint2(cvt_pk_bf16(v[0], v[1]), cvt_pk_bf16(v[2], v[3]));
          const int sel = n0 >> 10, rem = n0 & 1023;
          if (sel == 0)
            *(uint2*)&oq[((size_t)(b * 16 + (rem >> 6)) * 2048 + t) * 64 + (rem & 63)] = pk;
          else if (sel == 1)
            *(uint2*)&ok_[((size_t)(b * 16 + (rem >> 6)) * 2048 + t) * 64 + (rem & 63)] = pk;
          else
            *(uint2*)&ov[(size_t)(b * 2048 + t) * 1024 + rem] = pk;
        } else if (n0 < 4096) {
          const float4 b4 = *(const float4*)&bias2[n0 - 3072];
          v[0] += b4.x; v[1] += b4.y; v[2] += b4.z; v[3] += b4.w;
          *(f32x4*)&omv[(size_t)(b * 2048 + t) * 1024 + n0 - 3072] = v;
        } else if (n0 < 4368) {
          *(f32x4*)&ocs[(size_t)(b * 2048 + t) * 272 + n0 - 4096] = v;
        }
      }
    }
  }
}

// -------- V transpose + PV k-permute: vtmp [b,t,(h,dh)] -> vb [b,h,dh,tau(t)] --------
__global__ __launch_bounds__(256) void k_vtrans(const short* __restrict__ vtmp,
                                                short* __restrict__ vb) {
  __shared__ short tile[64][68];
  const int bh = blockIdx.x, b = bh >> 4, h = bh & 15;
  const int t0 = blockIdx.y * 64;
  const int tid = threadIdx.x;
#pragma unroll
  for (int pass = 0; pass < 16; ++pass) {
    int r = pass * 4 + (tid >> 6);
    int c = tid & 63;
    tile[r][c] = vtmp[((size_t)(b * 2048) + t0 + r) * 1024 + h * 64 + c];
  }
  __syncthreads();
#pragma unroll
  for (int pass = 0; pass < 16; ++pass) {
    int r = pass * 4 + (tid >> 6);  // dh
    int c = tid & 63;               // t offset within tile
    int cp = (c & 32) | (((c >> 2) & 3) << 3) | (((c >> 4) & 1) << 2) | (c & 3);
    vb[(((size_t)b * 16 + h) * 64 + r) * 2048 + t0 + cp] = tile[c][r];
  }
}

// ---------------- causal flash attention, swapped-operand, balanced pairs -----------
#define ATT_SCALE 0.18033688f  // 0.125 * log2(e)

__device__ __forceinline__ void attn_core(const bf16x8 qa[2], f32x4 o[4],
                                          float& m, float& l,
                                          const short* __restrict__ Kc,
                                          const short* __restrict__ Vc,
                                          int qt, int kt, int qglob,
                                          int ql, int g) {
  const int kv0 = kt * 64;
  f32x4 s4[4];
#pragma unroll
  for (int nt = 0; nt < 4; ++nt) {
    int krow = nt * 16 + ql;
    f32x4 s = {0.f, 0.f, 0.f, 0.f};
#pragma unroll
    for (int kc = 0; kc < 2; ++kc) {
      int sl = (kc * 4 + g) ^ (krow & 7);
      bf16x8 af = *(const bf16x8*)&Kc[krow * 64 + sl * 8];
      s = __builtin_amdgcn_mfma_f32_16x16x32_bf16(af, qa[kc], s, 0, 0, 0);
    }
    s4[nt] = s;
  }
  float mt = -1e30f;
  const bool diag = (kt == qt);
#pragma unroll
  for (int nt = 0; nt < 4; ++nt)
#pragma unroll
    for (int rg = 0; rg < 4; ++rg) {
      float v = s4[nt][rg] * ATT_SCALE;
      if (diag) {
        int kk = kv0 + nt * 16 + g * 4 + rg;
        v = (kk <= qglob) ? v : -1e30f;
      }
      s4[nt][rg] = v;
      mt = fmaxf(mt, v);
    }
  mt = fmaxf(mt, __shfl_xor(mt, 16, 64));
  mt = fmaxf(mt, __shfl_xor(mt, 32, 64));
  float mnew = fmaxf(m, mt);
  float sf = __builtin_amdgcn_exp2f(m - mnew);
  m = mnew;
  float rs = 0.f;
#pragma unroll
  for (int nt = 0; nt < 4; ++nt)
#pragma unroll
    for (int rg = 0; rg < 4; ++rg) {
      float p = __builtin_amdgcn_exp2f(s4[nt][rg] - mnew);
      s4[nt][rg] = p;
      rs += p;
    }
  rs += __shfl_xor(rs, 16, 64);
  rs += __shfl_xor(rs, 32, 64);
  l = l * sf + rs;
#pragma unroll
  for (int nt = 0; nt < 4; ++nt) o[nt] *= sf;
  bf16x8 pf[2];
#pragma unroll
  for (int kc = 0; kc < 2; ++kc) {
    u32x4 w;
    w[0] = cvt_pk_bf16(s4[2 * kc][0], s4[2 * kc][1]);
    w[1] = cvt_pk_bf16(s4[2 * kc][2], s4[2 * kc][3]);
    w[2] = cvt_pk_bf16(s4[2 * kc + 1][0], s4[2 * kc + 1][1]);
    w[3] = cvt_pk_bf16(s4[2 * kc + 1][2], s4[2 * kc + 1][3]);
    pf[kc] = __builtin_bit_cast(bf16x8, w);
  }
#pragma unroll
  for (int nt2 = 0; nt2 < 4; ++nt2) {
    int d = nt2 * 16 + ql;
#pragma unroll
    for (int kc = 0; kc < 2; ++kc) {
      int sl = (kc * 4 + g) ^ (d & 7);
      bf16x8 vf = *(const bf16x8*)&Vc[d * 64 + sl * 8];
      o[nt2] = __builtin_amdgcn_mfma_f32_16x16x32_bf16(vf, pf[kc], o[nt2], 0, 0, 0);
    }
  }
}

__device__ __forceinline__ void attn_epi(const f32x4 o[4], float l,
                                         short* __restrict__ seqo, float* ep,
                                         int b, int h, int qt, int wave, int lane) {
  const int ql = lane & 15, g = lane >> 4;
  float inv = 1.f / l;
#pragma unroll
  for (int nt2 = 0; nt2 < 4; ++nt2) {
    f32x4 v = o[nt2] * inv;
    *(f32x4*)&ep[ql * 64 + (((nt2 * 4 + g) ^ (ql & 7)) << 2)] = v;
  }
  short* srow = seqo + ((size_t)b * 2048 + qt * 64 + wave * 16) * 1024 + h * 64;
#pragma unroll
  for (int p = 0; p < 8; ++p) {
    int prow = p * 2 + (lane >> 5);
    int d2 = (lane & 31) * 2;
    const float* rp = &ep[prow * 64 + (((d2 >> 2) ^ (prow & 7)) << 2) + (d2 & 3)];
    float2 vv = *(const float2*)rp;
    *(unsigned*)&srow[(size_t)prow * 1024 + d2] = cvt_pk_bf16(vv.x, vv.y);
  }
}

__global__ __launch_bounds__(512, 4) void k_attn(const short* __restrict__ Q,
                                                 const short* __restrict__ Kg,
                                                 const short* __restrict__ Vg,
                                                 short* __restrict__ seqo) {
  __shared__ short Kt[2][2][64 * 64];  // [half][buf]
  __shared__ short Vt[2][2][64 * 64];
  const int wg = blockIdx.x;
  const int x = wg & 7, s = wg >> 3;
  const int bh = 4 * x + (s >> 3);
  const int tid = threadIdx.x;
  const int half = tid >> 8;
  const int pi = ((s & 7) << 1) + half;
  const int qtA = pi, qtB = 31 - pi;
  const int b = bh >> 4, h = bh & 15;
  const int wave = (tid >> 6) & 3, lane = tid & 63;
  const int ql = lane & 15, g = lane >> 4;
  const short* qbase = Q + (size_t)bh * 2048 * 64;
  const int qgA = qtA * 64 + wave * 16 + ql;
  const int qgB = qtB * 64 + wave * 16 + ql;
  bf16x8 qaA[2], qaB[2];
  {
    const short* qr = qbase + (size_t)qgA * 64;
    qaA[0] = *(const bf16x8*)&qr[g * 8];
    qaA[1] = *(const bf16x8*)&qr[32 + g * 8];
    qr = qbase + (size_t)qgB * 64;
    qaB[0] = *(const bf16x8*)&qr[g * 8];
    qaB[1] = *(const bf16x8*)&qr[32 + g * 8];
  }
  f32x4 oA[4] = {}, oB[4] = {};
  float mA = -1e30f, lA = 0.f, mB = -1e30f, lB = 0.f;
  const short* kgb = Kg + (size_t)bh * 2048 * 64;
  const short* vgb = Vg + (size_t)bh * 64 * 2048;

  auto stage = [&](int buf, int kt) {
    int kv0 = kt * 64;
#pragma unroll
    for (int j = 0; j < 2; ++j) {
      int slot = (wave * 2 + j) * 64 + lane;
      int r = slot >> 3, s8 = slot & 7;
      int ss = s8 ^ (r & 7);
      load_lds16(kgb + (size_t)(kv0 + r) * 64 + ss * 8, &Kt[half][buf][slot * 8]);
      load_lds16(vgb + (size_t)r * 2048 + kv0 + ss * 8, &Vt[half][buf][slot * 8]);
    }
  };

  stage(0, 0);
  int cur = 0;
  for (int it = 0; it < 33; ++it) {
    __syncthreads();
    if (it < 32) {
      int nit = it + 1;
      int nkt = (nit <= qtB) ? nit : nit - qtB - 1;
      stage(cur ^ 1, nkt);
    }
    const short* Kc = Kt[half][cur];
    const short* Vc = Vt[half][cur];
    if (it <= qtB)
      attn_core(qaB, oB, mB, lB, Kc, Vc, qtB, it, qgB, ql, g);
    else
      attn_core(qaA, oA, mA, lA, Kc, Vc, qtA, it - qtB - 1, qgA, ql, g);
    cur ^= 1;
  }
  __syncthreads();
  float* ep = (float*)&Kt[half][0][0] + wave * 1024;
  attn_epi(oB, lB, seqo, ep, b, h, qtB, wave, lane);
  attn_epi(oA, lA, seqo, ep, b, h, qtA, wave, lane);
}

// ---------------- Plücker lines: Csm [b,t,272] -> u=(wl@J)/|wl|, r=rl/|rl| ----------
__global__ __launch_bounds__(256) void k_lines(const float* __restrict__ Cs,
                                               const float* __restrict__ Jm,
                                               float* __restrict__ u,
                                               float* __restrict__ rr) {
  int idx = blockIdx.x * 256 + threadIdx.x;
  if (idx >= 2 * 2048 * 16) return;
  int h = idx & 15, t = (idx >> 4) & 2047, b = idx >> 15;
  const float* rowx = Cs + (size_t)(b * 2048 + t) * 272;
  float w1[4], w2[4], r1[4], r2[4];
  if (t == 0) {
#pragma unroll
    for (int i = 0; i < 4; ++i) w1[i] = 0.f;
  } else {
    const float* prev = Cs + (size_t)(b * 2048 + t - 1) * 272;
#pragma unroll
    for (int i = 0; i < 4; ++i) w1[i] = prev[h * 4 + i];
  }
#pragma unroll
  for (int i = 0; i < 4; ++i) {
    w2[i] = rowx[64 + h * 4 + i];
    r1[i] = rowx[128 + h * 4 + i];
    r2[i] = rowx[192 + h * 4 + i];
  }
  const int pi[6] = {0, 0, 0, 1, 1, 2}, pj[6] = {1, 2, 3, 2, 3, 3};
  float wl[6], rl[6], nw = 0.f, nr = 0.f;
#pragma unroll
  for (int e = 0; e < 6; ++e) {
    wl[e] = w1[pi[e]] * w2[pj[e]] - w1[pj[e]] * w2[pi[e]];
    rl[e] = r1[pi[e]] * r2[pj[e]] - r1[pj[e]] * r2[pi[e]];
    nw += wl[e] * wl[e];
    nr += rl[e] * rl[e];
  }
  nw = 1.f / fmaxf(sqrtf(nw), 1e-12f);
  nr = 1.f / fmaxf(sqrtf(nr), 1e-12f);
  size_t base = (((size_t)b * 16 + h) * 2048 + t) * 6;
#pragma unroll
  for (int jc = 0; jc < 6; ++jc) {
    float s = 0.f;
#pragma unroll
    for (int i = 0; i < 6; ++i) s += wl[i] * Jm[i * 6 + jc];
    u[base + jc] = s * nw;
    rr[base + jc] = rl[jc] * nr;
  }
}

// ------------- decayed prefix scan per channel: w[bh][ch][t] = S_t[p][q] -------------
__global__ __launch_bounds__(256) void k_scanw(const float* __restrict__ u,
                                               float* __restrict__ w,
                                               const float* __restrict__ decays) {
  __shared__ float wtot[4];
  const int ch = blockIdx.x;   // 0..35
  const int bh = blockIdx.y;   // 0..31
  const float d = decays[bh & 15];
  const int p = ch / 6, q = ch % 6;
  const int tid = threadIdx.x, lane = tid & 63, wv = tid >> 6;
  const float* ub = u + (size_t)bh * 2048 * 6;
  const int t0 = tid * 8;
  float z[8];
  float a = 0.f;
#pragma unroll
  for (int i = 0; i < 8; ++i) {
    float up = ub[(t0 + i) * 6 + p], uq = ub[(t0 + i) * 6 + q];
    z[i] = up * uq;
    a = d * (a + z[i]);
  }
  float d8 = d * d; d8 *= d8; d8 *= d8;
  float I = a;
  float ds = d8;
#pragma unroll
  for (int s = 1; s < 64; s <<= 1) {
    float v = __shfl_up(I, s, 64);
    if (lane >= s) I += ds * v;
    ds *= ds;
  }
  if (lane == 63) wtot[wv] = I;
  __syncthreads();
  float carry = 0.f;
  for (int w2 = 0; w2 < wv; ++w2) carry = carry * ds + wtot[w2];
  float dlp1 = exp2f(log2f(d8) * (float)(lane + 1));
  float Ig = I + dlp1 * carry;
  float E = __shfl_up(Ig, 1, 64);
  if (lane == 0) E = carry;
  float S = E;
  float out[8];
#pragma unroll
  for (int i = 0; i < 8; ++i) {
    out[i] = S;
    S = d * (S + z[i]);
  }
  float4* wp = (float4*)(w + ((size_t)bh * 36 + ch) * 2048 + t0);
  wp[0] = make_float4(out[0], out[1], out[2], out[3]);
  wp[1] = make_float4(out[4], out[5], out[6], out[7]);
}

// ------------- scores[bh][t] = sum_ch r[p]*r[q] * w[bh][ch][t] ----------------------
__global__ __launch_bounds__(256) void k_scandot(const float* __restrict__ rr,
                                                 const float* __restrict__ w,
                                                 float* __restrict__ scores) {
  const int bh = blockIdx.y;
  const int t = blockIdx.x * 256 + threadIdx.x;
  const float* rb = rr + ((size_t)bh * 2048 + t) * 6;
  float r[6];
#pragma unroll
  for (int i = 0; i < 6; ++i) r[i] = rb[i];
  const float* wb = w + (size_t)bh * 36 * 2048 + t;
  float acc = 0.f;
#pragma unroll
  for (int ch = 0; ch < 36; ++ch)
    acc += r[ch / 6] * r[ch % 6] * wb[(size_t)ch * 2048];
  scores[(size_t)bh * 2048 + t] = acc;
}

// ---------------- gate: gmean[b,t] = mean_h sig(score*scale_h)*sig(memg) -----------
__global__ __launch_bounds__(256) void k_gate(const float* __restrict__ scores,
                                              const float* __restrict__ Cs,
                                              const float* __restrict__ memg_b,
                                              const float* __restrict__ mem_scale,
                                              float* __restrict__ gmean) {
  int idx = blockIdx.x * 256 + threadIdx.x;
  if (idx >= BT) return;
  int b = idx >> 11, t = idx & 2047;
  float acc = 0.f;
#pragma unroll
  for (int h = 0; h < 16; ++h) {
    float s = scores[((size_t)(b * 16 + h) * 2048) + t];
    float gl = Cs[(size_t)idx * 272 + 256 + h] + memg_b[h];
    float a = 1.f / (1.f + __expf(-s * mem_scale[h]));
    float gg = 1.f / (1.f + __expf(-gl));
    acc += a * gg;
  }
  gmean[idx] = acc * (1.f / 16.f);
}

// ---------------- fuse: Fb = bf16(seq_bf16 + gmean*memval) ----------------
__global__ __launch_bounds__(256) void k_fuse(const short* __restrict__ s,
                                              const float* __restrict__ mv,
                                              const float* __restrict__ gm,
                                              short* __restrict__ dst, int n4) {
  int i = blockIdx.x * 256 + threadIdx.x;
  if (i >= n4) return;
  float gg = gm[i >> 8];
  short4 a = ((const short4*)s)[i];
  float4 m = ((const float4*)mv)[i];
  short4 o;
  o.x = f2bf(bf2f(a.x) + gg * m.x);
  o.y = f2bf(bf2f(a.y) + gg * m.y);
  o.z = f2bf(bf2f(a.z) + gg * m.z);
  o.w = f2bf(bf2f(a.w) + gg * m.w);
  ((short4*)dst)[i] = o;
}

extern "C" void kernel_launch(void* const* d_in, const int* in_sizes, int n_in,
                              void* d_out, int out_size, void* d_ws, size_t ws_size,
                              hipStream_t stream) {
  const float* x = (const float*)d_in[0];
  const float* qkv_w = (const float*)d_in[1];
  const float* qkv_b = (const float*)d_in[2];
  const float* w1w = (const float*)d_in[3];
  const float* w2w = (const float*)d_in[4];
  const float* w1r = (const float*)d_in[5];
  const float* w2r = (const float*)d_in[6];
  const float* memv_w = (const float*)d_in[7];
  const float* memv_b = (const float*)d_in[8];
  const float* memg_w = (const float*)d_in[9];
  const float* memg_b = (const float*)d_in[10];
  const float* mem_scale = (const float*)d_in[11];
  const float* out_w = (const float*)d_in[12];
  const float* out_b = (const float*)d_in[13];
  const float* Jm = (const float*)d_in[14];
  const float* decays = (const float*)d_in[15];

  char* w = (char*)d_ws;
  size_t off = 0;
  auto alloc = [&](size_t bytes) -> void* {
    void* p = w + off;
    off += (bytes + 255) & ~(size_t)255;
    return p;
  };
  short* xb = (short*)alloc((size_t)BT * Dd * 2);
  short* WTall = (short*)alloc((size_t)4480 * 1024 * 2);  // qkv|memv|sm|pad
  short* WTout = (short*)alloc((size_t)1024 * 1024 * 2);
  short* qb = (short*)alloc((size_t)32 * 2048 * 64 * 2);
  short* kb = (short*)alloc((size_t)32 * 2048 * 64 * 2);
  short* vtmp = (short*)alloc((size_t)BT * 1024 * 2);
  short* vb = (short*)alloc((size_t)32 * 64 * 2048 * 2);
  float* Csm = (float*)alloc((size_t)BT * 272 * 4);
  float* ua = (float*)alloc((size_t)32 * 2048 * 6 * 4);
  float* ra = (float*)alloc((size_t)32 * 2048 * 6 * 4);
  float* sc = (float*)alloc((size_t)32 * 2048 * 4);
  float* gm = (float*)alloc((size_t)BT * 4);
  float* mval = (float*)alloc((size_t)BT * 1024 * 4);
  short* seqo = (short*)alloc((size_t)BT * 1024 * 2);
  short* Fb = (short*)alloc((size_t)BT * Dd * 2);
  float* wscan = (float*)qb;  // aliases qb+kb, dead after k_attn
  (void)ws_size; (void)in_sizes; (void)n_in; (void)out_size;

  // prep
  hipMemsetAsync(WTall + (size_t)4368 * 1024, 0, (size_t)112 * 1024 * 2, stream);
  k_cvt<<<(BT * Dd / 4 + 255) / 256, 256, 0, stream>>>(x, xb, BT * Dd / 4);
  k_wt2<<<dim3(48, 16), 256, 0, stream>>>(qkv_w, WTall, 1024, 3072);
  k_wt2<<<dim3(16, 16), 256, 0, stream>>>(memv_w, WTall + (size_t)3072 * 1024, 1024, 1024);
  k_wt5<<<dim3(1, 16, 5), 256, 0, stream>>>(w1w, w2w, w1r, w2r, memg_w, WTall);
  k_wt2<<<dim3(16, 16), 256, 0, stream>>>(out_w, WTout, 1024, 1024);

  // fused GEMM: qkv (3072) | memv (1024) | sm (272) over N=4480
  k_gemm<<<dim3(35, 32), 256, 0, stream>>>(xb, WTall, qkv_b, nullptr, memv_b,
                                           qb, kb, vtmp, mval, Csm, 1024, 0, 1);
  k_vtrans<<<dim3(32, 32), 256, 0, stream>>>(vtmp, vb);

  // attention: 256 balanced blocks x 512 threads
  k_attn<<<256, 512, 0, stream>>>(qb, kb, vb, seqo);

  // memory path
  k_lines<<<(2 * 2048 * 16 + 255) / 256, 256, 0, stream>>>(Csm, Jm, ua, ra);
  k_scanw<<<dim3(36, 32), 256, 0, stream>>>(ua, wscan, decays);
  k_scandot<<<dim3(8, 32), 256, 0, stream>>>(ra, wscan, sc);
  k_gate<<<(BT + 255) / 256, 256, 0, stream>>>(sc, Csm, memg_b, mem_scale, gm);

  // fuse + final GEMM
  k_fuse<<<(BT * Dd / 4 + 255) / 256, 256, 0, stream>>>(seqo, mval, gm, Fb, BT * Dd / 4);
  k_gemm<<<dim3(8, 32), 256, 0, stream>>>(Fb, WTout, out_b, (float*)d_out, nullptr,
                                          nullptr, nullptr, nullptr, nullptr, nullptr,
                                          1024, 1024, 0);
}

// Round 6
// 223.734 us; speedup vs baseline: 1.3573x; 1.0107x over previous
//
#include <hip/hip_runtime.h>

#define BT 4096      // B*T
#define Dd 1024
#define Tt 2048

typedef __attribute__((ext_vector_type(8))) short bf16x8;
typedef __attribute__((ext_vector_type(4))) float f32x4;
typedef __attribute__((ext_vector_type(4))) unsigned u32x4;

__device__ __forceinline__ short f2bf(float f) {
  unsigned u = __builtin_bit_cast(unsigned, f);
  u = (u + 0x7FFFu + ((u >> 16) & 1u)) >> 16;
  return (short)u;
}
__device__ __forceinline__ float bf2f(short s) {
  unsigned u = ((unsigned)(unsigned short)s) << 16;
  return __builtin_bit_cast(float, u);
}
__device__ __forceinline__ unsigned cvt_pk_bf16(float a, float b) {
  unsigned r;
  asm("v_cvt_pk_bf16_f32 %0, %1, %2" : "=v"(r) : "v"(a), "v"(b));
  return r;
}

__device__ __forceinline__ void load_lds16(const void* gsrc, void* ldst) {
  __builtin_amdgcn_global_load_lds(
      (const __attribute__((address_space(1))) void*)gsrc,
      (__attribute__((address_space(3))) void*)ldst, 16, 0, 0);
}

// ---------------- x fp32 -> bf16 ----------------
__global__ __launch_bounds__(256) void k_cvt(const float* __restrict__ src,
                                             short* __restrict__ dst, int n4) {
  int i = blockIdx.x * 256 + threadIdx.x;
  if (i >= n4) return;
  float4 v = ((const float4*)src)[i];
  short4 o;
  o.x = f2bf(v.x); o.y = f2bf(v.y); o.z = f2bf(v.z); o.w = f2bf(v.w);
  ((short4*)dst)[i] = o;
}

// ------------- tiled weight transpose: src [K][N] f32 -> dst [N][K] bf16 -------------
__global__ __launch_bounds__(256) void k_wt2(const float* __restrict__ src,
                                             short* __restrict__ dst, int K, int N) {
  __shared__ float tile[64][65];
  const int n0 = blockIdx.x * 64, k0 = blockIdx.y * 64;
  const int c = threadIdx.x & 63, r4 = threadIdx.x >> 6;
#pragma unroll
  for (int i = 0; i < 16; ++i) {
    int r = i * 4 + r4;
    float v = 0.f;
    if (k0 + r < K && n0 + c < N) v = src[(size_t)(k0 + r) * N + n0 + c];
    tile[r][c] = v;
  }
  __syncthreads();
#pragma unroll
  for (int i = 0; i < 16; ++i) {
    int n = i * 4 + r4;
    if (n0 + n < N && k0 + c < K)
      dst[(size_t)(n0 + n) * K + k0 + c] = f2bf(tile[c][n]);
  }
}

// ------- batched small transposes into WTall rows 4096.. (w1w,w2w,w1r,w2r,memg) -----
__global__ __launch_bounds__(256) void k_wt5(const float* __restrict__ s0,
                                             const float* __restrict__ s1,
                                             const float* __restrict__ s2,
                                             const float* __restrict__ s3,
                                             const float* __restrict__ s4,
                                             short* __restrict__ dst) {
  __shared__ float tile[64][65];
  const int z = blockIdx.z;
  const float* src = z == 0 ? s0 : z == 1 ? s1 : z == 2 ? s2 : z == 3 ? s3 : s4;
  const int N = (z == 4) ? 16 : 64;
  const int rowoff = 4096 + z * 64;
  const int k0 = blockIdx.y * 64;
  const int c = threadIdx.x & 63, r4 = threadIdx.x >> 6;
#pragma unroll
  for (int i = 0; i < 16; ++i) {
    int r = i * 4 + r4;
    float v = 0.f;
    if (c < N) v = src[(size_t)(k0 + r) * N + c];
    tile[r][c] = v;
  }
  __syncthreads();
#pragma unroll
  for (int i = 0; i < 16; ++i) {
    int n = i * 4 + r4;
    if (n < N)
      dst[(size_t)(rowoff + n) * 1024 + k0 + c] = f2bf(tile[c][n]);
  }
}

// ------- bf16 MFMA GEMM, 3-deep counted-vmcnt pipeline, chunk-swizzled LDS ----------
// acc = mfma(B_frag, A_frag): lane owns C row m (lane&15) and 4 consecutive cols/reg.
// LDS swizzle: phys 16B-chunk u = (c + (row>>1)) & 3 (applied at global source on
// stage and at fragment read) -> 8-way bank conflict becomes free 2-way.
// mode 0: C[m][n] fp32 (ldc) + bias.   mode 1: fused routing (qkv|memv|Csm).
__global__ __launch_bounds__(256) void k_gemm(
    const short* __restrict__ A, const short* __restrict__ Bt,
    const float* __restrict__ bias, float* __restrict__ C,
    const float* __restrict__ bias2,
    short* __restrict__ oq, short* __restrict__ ok_, short* __restrict__ ov,
    float* __restrict__ omv, float* __restrict__ ocs,
    int K, int ldc, int mode) {
  __shared__ short As[3][128 * 32];
  __shared__ short Bs[3][128 * 32];
  const int tid = threadIdx.x;
  const int wave = tid >> 6, lane = tid & 63;
  // XCD-chunked bijective remap: each XCD owns gridDim.y/8 M-panels x all N.
  const int wg = blockIdx.y * gridDim.x + blockIdx.x;
  const int xcd = wg & 7, idx = wg >> 3;
  const int m_t = xcd * (gridDim.y >> 3) + idx / gridDim.x;
  const int n_t = idx % gridDim.x;
  const int bm = m_t * 128, bn = n_t * 128;
  const int wr = (wave >> 1) * 64, wc = (wave & 1) * 64;
  const int ql = lane & 15, g = lane >> 4;
  f32x4 acc[4][4] = {};
  const int kTiles = K >> 5;

  auto stage = [&](int buf, int kt) {
    const int k0 = kt << 5;
#pragma unroll
    for (int j = 0; j < 2; ++j) {
      int slot = (wave * 2 + j) * 64 + lane;
      int r = slot >> 2, u = slot & 3;
      int c = (u + 4 - ((r >> 1) & 3)) & 3;  // logical chunk for phys chunk u
      load_lds16(A + (size_t)(bm + r) * K + k0 + c * 8, &As[buf][slot * 8]);
      load_lds16(Bt + (size_t)(bn + r) * K + k0 + c * 8, &Bs[buf][slot * 8]);
    }
  };

  stage(0, 0);
  stage(1, 1);
  int cur = 0;
  for (int kt = 0; kt < kTiles; ++kt) {
    // wait for tile kt's 4 loads (tile kt+1's 4 stay in flight), sync waves
    if (kt + 1 < kTiles)
      asm volatile("s_waitcnt vmcnt(4)\n\ts_barrier" ::: "memory");
    else
      asm volatile("s_waitcnt vmcnt(0)\n\ts_barrier" ::: "memory");
    if (kt + 2 < kTiles) {
      int b2 = cur + 2; if (b2 >= 3) b2 -= 3;
      stage(b2, kt + 2);
    }
    bf16x8 af[4], bfr[4];
#pragma unroll
    for (int mi = 0; mi < 4; ++mi) {
      int row = wr + mi * 16 + ql;
      int ph = (g + (row >> 1)) & 3;
      af[mi] = *(const bf16x8*)&As[cur][row * 32 + ph * 8];
    }
#pragma unroll
    for (int ni = 0; ni < 4; ++ni) {
      int row = wc + ni * 16 + ql;
      int ph = (g + (row >> 1)) & 3;
      bfr[ni] = *(const bf16x8*)&Bs[cur][row * 32 + ph * 8];
    }
#pragma unroll
    for (int mi = 0; mi < 4; ++mi)
#pragma unroll
      for (int ni = 0; ni < 4; ++ni)
        acc[mi][ni] = __builtin_amdgcn_mfma_f32_16x16x32_bf16(bfr[ni], af[mi],
                                                              acc[mi][ni], 0, 0, 0);
    cur = (cur + 1 == 3) ? 0 : cur + 1;
  }
  // epilogue: lane owns row m = bm+wr+mi*16+ql, cols n0..n0+3 per (ni)
#pragma unroll
  for (int mi = 0; mi < 4; ++mi) {
    const int m = bm + wr + mi * 16 + ql;
    const int b = m >> 11, t = m & 2047;
#pragma unroll
    for (int ni = 0; ni < 4; ++ni) {
      const int n0 = bn + wc + ni * 16 + g * 4;
      f32x4 v = acc[mi][ni];
      if (mode == 0) {
        const float4 b4 = *(const float4*)&bias[n0];
        v[0] += b4.x; v[1] += b4.y; v[2] += b4.z; v[3] += b4.w;
        *(f32x4*)&C[(size_t)m * ldc + n0] = v;
      } else {
        if (n0 < 3072) {
          const float4 b4 = *(const float4*)&bias[n0];
          v[0] += b4.x; v[1] += b4.y; v[2] += b4.z; v[3] += b4.w;
          uint2 pk = make_uint2(cvt_pk_bf16(v[0], v[1]), cvt_pk_bf16(v[2], v[3]));
          const int sel = n0 >> 10, rem = n0 & 1023;
          if (sel == 0)
            *(uint2*)&oq[((size_t)(b * 16 + (rem >> 6)) * 2048 + t) * 64 + (rem & 63)] = pk;
          else if (sel == 1)
            *(uint2*)&ok_[((size_t)(b * 16 + (rem >> 6)) * 2048 + t) * 64 + (rem & 63)] = pk;
          else
            *(uint2*)&ov[(size_t)(b * 2048 + t) * 1024 + rem] = pk;
        } else if (n0 < 4096) {
          const float4 b4 = *(const float4*)&bias2[n0 - 3072];
          v[0] += b4.x; v[1] += b4.y; v[2] += b4.z; v[3] += b4.w;
          *(f32x4*)&omv[(size_t)(b * 2048 + t) * 1024 + n0 - 3072] = v;
        } else if (n0 < 4368) {
          *(f32x4*)&ocs[(size_t)(b * 2048 + t) * 272 + n0 - 4096] = v;
        }
      }
    }
  }
}

// -------- V transpose + PV k-permute: vtmp [b,t,(h,dh)] -> vb [b,h,dh,tau(t)] --------
__global__ __launch_bounds__(256) void k_vtrans(const short* __restrict__ vtmp,
                                                short* __restrict__ vb) {
  __shared__ short tile[64][68];
  const int bh = blockIdx.x, b = bh >> 4, h = bh & 15;
  const int t0 = blockIdx.y * 64;
  const int tid = threadIdx.x;
#pragma unroll
  for (int pass = 0; pass < 16; ++pass) {
    int r = pass * 4 + (tid >> 6);
    int c = tid & 63;
    tile[r][c] = vtmp[((size_t)(b * 2048) + t0 + r) * 1024 + h * 64 + c];
  }
  __syncthreads();
#pragma unroll
  for (int pass = 0; pass < 16; ++pass) {
    int r = pass * 4 + (tid >> 6);  // dh
    int c = tid & 63;               // t offset within tile
    int cp = (c & 32) | (((c >> 2) & 3) << 3) | (((c >> 4) & 1) << 2) | (c & 3);
    vb[(((size_t)b * 16 + h) * 64 + r) * 2048 + t0 + cp] = tile[c][r];
  }
}

// ---------------- causal flash attention, swapped-operand, balanced pairs -----------
#define ATT_SCALE 0.18033688f  // 0.125 * log2(e)

__device__ __forceinline__ void attn_core(const bf16x8 qa[2], f32x4 o[4],
                                          float& m, float& l,
                                          const short* __restrict__ Kc,
                                          const short* __restrict__ Vc,
                                          int qt, int kt, int qglob,
                                          int ql, int g) {
  const int kv0 = kt * 64;
  f32x4 s4[4];
#pragma unroll
  for (int nt = 0; nt < 4; ++nt) {
    int krow = nt * 16 + ql;
    f32x4 s = {0.f, 0.f, 0.f, 0.f};
#pragma unroll
    for (int kc = 0; kc < 2; ++kc) {
      int sl = (kc * 4 + g) ^ (krow & 7);
      bf16x8 af = *(const bf16x8*)&Kc[krow * 64 + sl * 8];
      s = __builtin_amdgcn_mfma_f32_16x16x32_bf16(af, qa[kc], s, 0, 0, 0);
    }
    s4[nt] = s;
  }
  float mt = -1e30f;
  const bool diag = (kt == qt);
#pragma unroll
  for (int nt = 0; nt < 4; ++nt)
#pragma unroll
    for (int rg = 0; rg < 4; ++rg) {
      float v = s4[nt][rg] * ATT_SCALE;
      if (diag) {
        int kk = kv0 + nt * 16 + g * 4 + rg;
        v = (kk <= qglob) ? v : -1e30f;
      }
      s4[nt][rg] = v;
      mt = fmaxf(mt, v);
    }
  mt = fmaxf(mt, __shfl_xor(mt, 16, 64));
  mt = fmaxf(mt, __shfl_xor(mt, 32, 64));
  float mnew = fmaxf(m, mt);
  float sf = __builtin_amdgcn_exp2f(m - mnew);
  m = mnew;
  float rs = 0.f;
#pragma unroll
  for (int nt = 0; nt < 4; ++nt)
#pragma unroll
    for (int rg = 0; rg < 4; ++rg) {
      float p = __builtin_amdgcn_exp2f(s4[nt][rg] - mnew);
      s4[nt][rg] = p;
      rs += p;
    }
  rs += __shfl_xor(rs, 16, 64);
  rs += __shfl_xor(rs, 32, 64);
  l = l * sf + rs;
#pragma unroll
  for (int nt = 0; nt < 4; ++nt) o[nt] *= sf;
  bf16x8 pf[2];
#pragma unroll
  for (int kc = 0; kc < 2; ++kc) {
    u32x4 w;
    w[0] = cvt_pk_bf16(s4[2 * kc][0], s4[2 * kc][1]);
    w[1] = cvt_pk_bf16(s4[2 * kc][2], s4[2 * kc][3]);
    w[2] = cvt_pk_bf16(s4[2 * kc + 1][0], s4[2 * kc + 1][1]);
    w[3] = cvt_pk_bf16(s4[2 * kc + 1][2], s4[2 * kc + 1][3]);
    pf[kc] = __builtin_bit_cast(bf16x8, w);
  }
#pragma unroll
  for (int nt2 = 0; nt2 < 4; ++nt2) {
    int d = nt2 * 16 + ql;
#pragma unroll
    for (int kc = 0; kc < 2; ++kc) {
      int sl = (kc * 4 + g) ^ (d & 7);
      bf16x8 vf = *(const bf16x8*)&Vc[d * 64 + sl * 8];
      o[nt2] = __builtin_amdgcn_mfma_f32_16x16x32_bf16(vf, pf[kc], o[nt2], 0, 0, 0);
    }
  }
}

__device__ __forceinline__ void attn_epi(const f32x4 o[4], float l,
                                         short* __restrict__ seqo, float* ep,
                                         int b, int h, int qt, int wave, int lane) {
  const int ql = lane & 15, g = lane >> 4;
  float inv = 1.f / l;
#pragma unroll
  for (int nt2 = 0; nt2 < 4; ++nt2) {
    f32x4 v = o[nt2] * inv;
    *(f32x4*)&ep[ql * 64 + (((nt2 * 4 + g) ^ (ql & 7)) << 2)] = v;
  }
  short* srow = seqo + ((size_t)b * 2048 + qt * 64 + wave * 16) * 1024 + h * 64;
#pragma unroll
  for (int p = 0; p < 8; ++p) {
    int prow = p * 2 + (lane >> 5);
    int d2 = (lane & 31) * 2;
    const float* rp = &ep[prow * 64 + (((d2 >> 2) ^ (prow & 7)) << 2) + (d2 & 3)];
    float2 vv = *(const float2*)rp;
    *(unsigned*)&srow[(size_t)prow * 1024 + d2] = cvt_pk_bf16(vv.x, vv.y);
  }
}

__global__ __launch_bounds__(512, 4) void k_attn(const short* __restrict__ Q,
                                                 const short* __restrict__ Kg,
                                                 const short* __restrict__ Vg,
                                                 short* __restrict__ seqo) {
  __shared__ short Kt[2][2][64 * 64];  // [half][buf]
  __shared__ short Vt[2][2][64 * 64];
  const int wg = blockIdx.x;
  const int x = wg & 7, s = wg >> 3;
  const int bh = 4 * x + (s >> 3);
  const int tid = threadIdx.x;
  const int half = tid >> 8;
  const int pi = ((s & 7) << 1) + half;
  const int qtA = pi, qtB = 31 - pi;
  const int b = bh >> 4, h = bh & 15;
  const int wave = (tid >> 6) & 3, lane = tid & 63;
  const int ql = lane & 15, g = lane >> 4;
  const short* qbase = Q + (size_t)bh * 2048 * 64;
  const int qgA = qtA * 64 + wave * 16 + ql;
  const int qgB = qtB * 64 + wave * 16 + ql;
  bf16x8 qaA[2], qaB[2];
  {
    const short* qr = qbase + (size_t)qgA * 64;
    qaA[0] = *(const bf16x8*)&qr[g * 8];
    qaA[1] = *(const bf16x8*)&qr[32 + g * 8];
    qr = qbase + (size_t)qgB * 64;
    qaB[0] = *(const bf16x8*)&qr[g * 8];
    qaB[1] = *(const bf16x8*)&qr[32 + g * 8];
  }
  f32x4 oA[4] = {}, oB[4] = {};
  float mA = -1e30f, lA = 0.f, mB = -1e30f, lB = 0.f;
  const short* kgb = Kg + (size_t)bh * 2048 * 64;
  const short* vgb = Vg + (size_t)bh * 64 * 2048;

  auto stage = [&](int buf, int kt) {
    int kv0 = kt * 64;
#pragma unroll
    for (int j = 0; j < 2; ++j) {
      int slot = (wave * 2 + j) * 64 + lane;
      int r = slot >> 3, s8 = slot & 7;
      int ss = s8 ^ (r & 7);
      load_lds16(kgb + (size_t)(kv0 + r) * 64 + ss * 8, &Kt[half][buf][slot * 8]);
      load_lds16(vgb + (size_t)r * 2048 + kv0 + ss * 8, &Vt[half][buf][slot * 8]);
    }
  };

  stage(0, 0);
  int cur = 0;
  for (int it = 0; it < 33; ++it) {
    __syncthreads();
    if (it < 32) {
      int nit = it + 1;
      int nkt = (nit <= qtB) ? nit : nit - qtB - 1;
      stage(cur ^ 1, nkt);
    }
    const short* Kc = Kt[half][cur];
    const short* Vc = Vt[half][cur];
    if (it <= qtB)
      attn_core(qaB, oB, mB, lB, Kc, Vc, qtB, it, qgB, ql, g);
    else
      attn_core(qaA, oA, mA, lA, Kc, Vc, qtA, it - qtB - 1, qgA, ql, g);
    cur ^= 1;
  }
  __syncthreads();
  float* ep = (float*)&Kt[half][0][0] + wave * 1024;
  attn_epi(oB, lB, seqo, ep, b, h, qtB, wave, lane);
  attn_epi(oA, lA, seqo, ep, b, h, qtA, wave, lane);
}

// ---------------- Plücker lines: Csm [b,t,272] -> u=(wl@J)/|wl|, r=rl/|rl| ----------
__global__ __launch_bounds__(256) void k_lines(const float* __restrict__ Cs,
                                               const float* __restrict__ Jm,
                                               float* __restrict__ u,
                                               float* __restrict__ rr) {
  int idx = blockIdx.x * 256 + threadIdx.x;
  if (idx >= 2 * 2048 * 16) return;
  int h = idx & 15, t = (idx >> 4) & 2047, b = idx >> 15;
  const float* rowx = Cs + (size_t)(b * 2048 + t) * 272;
  float w1[4], w2[4], r1[4], r2[4];
  if (t == 0) {
#pragma unroll
    for (int i = 0; i < 4; ++i) w1[i] = 0.f;
  } else {
    const float* prev = Cs + (size_t)(b * 2048 + t - 1) * 272;
#pragma unroll
    for (int i = 0; i < 4; ++i) w1[i] = prev[h * 4 + i];
  }
#pragma unroll
  for (int i = 0; i < 4; ++i) {
    w2[i] = rowx[64 + h * 4 + i];
    r1[i] = rowx[128 + h * 4 + i];
    r2[i] = rowx[192 + h * 4 + i];
  }
  const int pi[6] = {0, 0, 0, 1, 1, 2}, pj[6] = {1, 2, 3, 2, 3, 3};
  float wl[6], rl[6], nw = 0.f, nr = 0.f;
#pragma unroll
  for (int e = 0; e < 6; ++e) {
    wl[e] = w1[pi[e]] * w2[pj[e]] - w1[pj[e]] * w2[pi[e]];
    rl[e] = r1[pi[e]] * r2[pj[e]] - r1[pj[e]] * r2[pi[e]];
    nw += wl[e] * wl[e];
    nr += rl[e] * rl[e];
  }
  nw = 1.f / fmaxf(sqrtf(nw), 1e-12f);
  nr = 1.f / fmaxf(sqrtf(nr), 1e-12f);
  size_t base = (((size_t)b * 16 + h) * 2048 + t) * 6;
#pragma unroll
  for (int jc = 0; jc < 6; ++jc) {
    float s = 0.f;
#pragma unroll
    for (int i = 0; i < 6; ++i) s += wl[i] * Jm[i * 6 + jc];
    u[base + jc] = s * nw;
    rr[base + jc] = rl[jc] * nr;
  }
}

// ------------- decayed prefix scan per channel: w[bh][ch][t] = S_t[p][q] -------------
__global__ __launch_bounds__(256) void k_scanw(const float* __restrict__ u,
                                               float* __restrict__ w,
                                               const float* __restrict__ decays) {
  __shared__ float wtot[4];
  const int ch = blockIdx.x;   // 0..35
  const int bh = blockIdx.y;   // 0..31
  const float d = decays[bh & 15];
  const int p = ch / 6, q = ch % 6;
  const int tid = threadIdx.x, lane = tid & 63, wv = tid >> 6;
  const float* ub = u + (size_t)bh * 2048 * 6;
  const int t0 = tid * 8;
  float z[8];
  float a = 0.f;
#pragma unroll
  for (int i = 0; i < 8; ++i) {
    float up = ub[(t0 + i) * 6 + p], uq = ub[(t0 + i) * 6 + q];
    z[i] = up * uq;
    a = d * (a + z[i]);
  }
  float d8 = d * d; d8 *= d8; d8 *= d8;
  float I = a;
  float ds = d8;
#pragma unroll
  for (int s = 1; s < 64; s <<= 1) {
    float v = __shfl_up(I, s, 64);
    if (lane >= s) I += ds * v;
    ds *= ds;
  }
  if (lane == 63) wtot[wv] = I;
  __syncthreads();
  float carry = 0.f;
  for (int w2 = 0; w2 < wv; ++w2) carry = carry * ds + wtot[w2];
  float dlp1 = exp2f(log2f(d8) * (float)(lane + 1));
  float Ig = I + dlp1 * carry;
  float E = __shfl_up(Ig, 1, 64);
  if (lane == 0) E = carry;
  float S = E;
  float out[8];
#pragma unroll
  for (int i = 0; i < 8; ++i) {
    out[i] = S;
    S = d * (S + z[i]);
  }
  float4* wp = (float4*)(w + ((size_t)bh * 36 + ch) * 2048 + t0);
  wp[0] = make_float4(out[0], out[1], out[2], out[3]);
  wp[1] = make_float4(out[4], out[5], out[6], out[7]);
}

// ------------- scores[bh][t] = sum_ch r[p]*r[q] * w[bh][ch][t] ----------------------
__global__ __launch_bounds__(256) void k_scandot(const float* __restrict__ rr,
                                                 const float* __restrict__ w,
                                                 float* __restrict__ scores) {
  const int bh = blockIdx.y;
  const int t = blockIdx.x * 256 + threadIdx.x;
  const float* rb = rr + ((size_t)bh * 2048 + t) * 6;
  float r[6];
#pragma unroll
  for (int i = 0; i < 6; ++i) r[i] = rb[i];
  const float* wb = w + (size_t)bh * 36 * 2048 + t;
  float acc = 0.f;
#pragma unroll
  for (int ch = 0; ch < 36; ++ch)
    acc += r[ch / 6] * r[ch % 6] * wb[(size_t)ch * 2048];
  scores[(size_t)bh * 2048 + t] = acc;
}

// ---------------- gate: gmean[b,t] = mean_h sig(score*scale_h)*sig(memg) -----------
__global__ __launch_bounds__(256) void k_gate(const float* __restrict__ scores,
                                              const float* __restrict__ Cs,
                                              const float* __restrict__ memg_b,
                                              const float* __restrict__ mem_scale,
                                              float* __restrict__ gmean) {
  int idx = blockIdx.x * 256 + threadIdx.x;
  if (idx >= BT) return;
  int b = idx >> 11, t = idx & 2047;
  float acc = 0.f;
#pragma unroll
  for (int h = 0; h < 16; ++h) {
    float s = scores[((size_t)(b * 16 + h) * 2048) + t];
    float gl = Cs[(size_t)idx * 272 + 256 + h] + memg_b[h];
    float a = 1.f / (1.f + __expf(-s * mem_scale[h]));
    float gg = 1.f / (1.f + __expf(-gl));
    acc += a * gg;
  }
  gmean[idx] = acc * (1.f / 16.f);
}

// ---------------- fuse: Fb = bf16(seq_bf16 + gmean*memval) ----------------
__global__ __launch_bounds__(256) void k_fuse(const short* __restrict__ s,
                                              const float* __restrict__ mv,
                                              const float* __restrict__ gm,
                                              short* __restrict__ dst, int n4) {
  int i = blockIdx.x * 256 + threadIdx.x;
  if (i >= n4) return;
  float gg = gm[i >> 8];
  short4 a = ((const short4*)s)[i];
  float4 m = ((const float4*)mv)[i];
  short4 o;
  o.x = f2bf(bf2f(a.x) + gg * m.x);
  o.y = f2bf(bf2f(a.y) + gg * m.y);
  o.z = f2bf(bf2f(a.z) + gg * m.z);
  o.w = f2bf(bf2f(a.w) + gg * m.w);
  ((short4*)dst)[i] = o;
}

extern "C" void kernel_launch(void* const* d_in, const int* in_sizes, int n_in,
                              void* d_out, int out_size, void* d_ws, size_t ws_size,
                              hipStream_t stream) {
  const float* x = (const float*)d_in[0];
  const float* qkv_w = (const float*)d_in[1];
  const float* qkv_b = (const float*)d_in[2];
  const float* w1w = (const float*)d_in[3];
  const float* w2w = (const float*)d_in[4];
  const float* w1r = (const float*)d_in[5];
  const float* w2r = (const float*)d_in[6];
  const float* memv_w = (const float*)d_in[7];
  const float* memv_b = (const float*)d_in[8];
  const float* memg_w = (const float*)d_in[9];
  const float* memg_b = (const float*)d_in[10];
  const float* mem_scale = (const float*)d_in[11];
  const float* out_w = (const float*)d_in[12];
  const float* out_b = (const float*)d_in[13];
  const float* Jm = (const float*)d_in[14];
  const float* decays = (const float*)d_in[15];

  char* w = (char*)d_ws;
  size_t off = 0;
  auto alloc = [&](size_t bytes) -> void* {
    void* p = w + off;
    off += (bytes + 255) & ~(size_t)255;
    return p;
  };
  short* xb = (short*)alloc((size_t)BT * Dd * 2);
  short* WTall = (short*)alloc((size_t)4480 * 1024 * 2);  // qkv|memv|sm|pad
  short* WTout = (short*)alloc((size_t)1024 * 1024 * 2);
  short* qb = (short*)alloc((size_t)32 * 2048 * 64 * 2);
  short* kb = (short*)alloc((size_t)32 * 2048 * 64 * 2);
  short* vtmp = (short*)alloc((size_t)BT * 1024 * 2);
  short* vb = (short*)alloc((size_t)32 * 64 * 2048 * 2);
  float* Csm = (float*)alloc((size_t)BT * 272 * 4);
  float* ua = (float*)alloc((size_t)32 * 2048 * 6 * 4);
  float* ra = (float*)alloc((size_t)32 * 2048 * 6 * 4);
  float* sc = (float*)alloc((size_t)32 * 2048 * 4);
  float* gm = (float*)alloc((size_t)BT * 4);
  float* mval = (float*)alloc((size_t)BT * 1024 * 4);
  short* seqo = (short*)alloc((size_t)BT * 1024 * 2);
  short* Fb = (short*)alloc((size_t)BT * Dd * 2);
  float* wscan = (float*)qb;  // aliases qb+kb, dead after k_attn
  (void)ws_size; (void)in_sizes; (void)n_in; (void)out_size;

  // prep
  hipMemsetAsync(WTall + (size_t)4368 * 1024, 0, (size_t)112 * 1024 * 2, stream);
  k_cvt<<<(BT * Dd / 4 + 255) / 256, 256, 0, stream>>>(x, xb, BT * Dd / 4);
  k_wt2<<<dim3(48, 16), 256, 0, stream>>>(qkv_w, WTall, 1024, 3072);
  k_wt2<<<dim3(16, 16), 256, 0, stream>>>(memv_w, WTall + (size_t)3072 * 1024, 1024, 1024);
  k_wt5<<<dim3(1, 16, 5), 256, 0, stream>>>(w1w, w2w, w1r, w2r, memg_w, WTall);
  k_wt2<<<dim3(16, 16), 256, 0, stream>>>(out_w, WTout, 1024, 1024);

  // fused GEMM: qkv (3072) | memv (1024) | sm (272) over N=4480
  k_gemm<<<dim3(35, 32), 256, 0, stream>>>(xb, WTall, qkv_b, nullptr, memv_b,
                                           qb, kb, vtmp, mval, Csm, 1024, 0, 1);
  k_vtrans<<<dim3(32, 32), 256, 0, stream>>>(vtmp, vb);

  // attention: 256 balanced blocks x 512 threads
  k_attn<<<256, 512, 0, stream>>>(qb, kb, vb, seqo);

  // memory path
  k_lines<<<(2 * 2048 * 16 + 255) / 256, 256, 0, stream>>>(Csm, Jm, ua, ra);
  k_scanw<<<dim3(36, 32), 256, 0, stream>>>(ua, wscan, decays);
  k_scandot<<<dim3(8, 32), 256, 0, stream>>>(ra, wscan, sc);
  k_gate<<<(BT + 255) / 256, 256, 0, stream>>>(sc, Csm, memg_b, mem_scale, gm);

  // fuse + final GEMM
  k_fuse<<<(BT * Dd / 4 + 255) / 256, 256, 0, stream>>>(seqo, mval, gm, Fb, BT * Dd / 4);
  k_gemm<<<dim3(8, 32), 256, 0, stream>>>(Fb, WTout, out_b, (float*)d_out, nullptr,
                                          nullptr, nullptr, nullptr, nullptr, nullptr,
                                          1024, 1024, 0);
}